// Round 5
// baseline (459.886 us; speedup 1.0000x reference)
//
#include <hip/hip_runtime.h>
#include <hip/hip_bf16.h>
#include <math.h>

#define NN 100000
#define NE 1000000

typedef __attribute__((ext_vector_type(8))) short bf16x8;
typedef __attribute__((ext_vector_type(4))) float f32x4;
typedef unsigned int u32;
typedef unsigned short u16;

__device__ __forceinline__ u16 f2b(float f) {
    __hip_bfloat16 h = __float2bfloat16(f);
    return *reinterpret_cast<u16*>(&h);
}
__device__ __forceinline__ float b2f(u16 u) {
    __hip_bfloat16 h = *reinterpret_cast<__hip_bfloat16*>(&u);
    return __bfloat162float(h);
}
__device__ __forceinline__ float bflo(u32 v) { return __uint_as_float(v << 16); }
__device__ __forceinline__ float bfhi(u32 v) { return __uint_as_float(v & 0xffff0000u); }

// ============================== CSR build ==============================

__global__ void hist_kernel(const int* __restrict__ dst, int* __restrict__ deg, int E) {
    int i = blockIdx.x * blockDim.x + threadIdx.x;
    if (i < E) atomicAdd(&deg[dst[i]], 1);
}

__global__ void scan_local(const int* __restrict__ deg, int* __restrict__ rowptr,
                           int* __restrict__ bsum, int N) {
    __shared__ int s[256];
    int i = blockIdx.x * 256 + threadIdx.x;
    int v = (i < N) ? deg[i] : 0;
    s[threadIdx.x] = v;
    __syncthreads();
    #pragma unroll
    for (int off = 1; off < 256; off <<= 1) {
        int t = (threadIdx.x >= off) ? s[threadIdx.x - off] : 0;
        __syncthreads();
        s[threadIdx.x] += t;
        __syncthreads();
    }
    if (i < N) rowptr[i + 1] = s[threadIdx.x];
    if (threadIdx.x == 255) bsum[blockIdx.x] = s[255];
}

__global__ void scan_bsum(int* __restrict__ bsum, int NB) {
    __shared__ int s[512];
    int v = (threadIdx.x < NB) ? bsum[threadIdx.x] : 0;
    s[threadIdx.x] = v;
    __syncthreads();
    for (int off = 1; off < 512; off <<= 1) {
        int t = (threadIdx.x >= off) ? s[threadIdx.x - off] : 0;
        __syncthreads();
        s[threadIdx.x] += t;
        __syncthreads();
    }
    if (threadIdx.x < NB) bsum[threadIdx.x] = s[threadIdx.x] - v;  // exclusive
}

__global__ void scan_add(int* __restrict__ rowptr, const int* __restrict__ bsum, int N) {
    int i = blockIdx.x * blockDim.x + threadIdx.x;
    if (i < N) rowptr[i + 1] += bsum[i >> 8];
    if (i == 0) rowptr[0] = 0;
}

__global__ void scatter_kernel(const int* __restrict__ src, const int* __restrict__ dst,
                               const int* __restrict__ rowptr, int* __restrict__ cnt,
                               int* __restrict__ csrc, int E) {
    int i = blockIdx.x * blockDim.x + threadIdx.x;
    if (i < E) {
        int d = dst[i];
        int pos = rowptr[d] + atomicAdd(&cnt[d], 1);
        csrc[pos] = src[i];
    }
}

// ============================== weight prep ==============================

__global__ void transW(const float* __restrict__ W, u16* __restrict__ Wt,
                       int K, int Nin, int NBpad) {
    int idx = blockIdx.x * 256 + threadIdx.x;
    if (idx < NBpad * K) {
        int n = idx / K, k = idx % K;
        float v = (n < Nin) ? W[(size_t)k * Nin + n] : 0.f;
        Wt[idx] = f2b(v);
    }
}

// ============================== MFMA GEMM ==============================
template<int K, int NT, int OUTW, bool OBF16, bool AF32>
__global__ __launch_bounds__(256) void gemm_mfma(const void* __restrict__ Ap_,
                                                 const u16* __restrict__ Wt,
                                                 void* __restrict__ Cp, int M) {
    constexpr int BK = 64;
    constexpr int ST = 72;
    constexpr int NB = NT * 16;
    __shared__ u16 lA[128 * ST];
    __shared__ u16 lB[NB * ST];
    const int tid = threadIdx.x;
    const int w = tid >> 6, l = tid & 63;
    const int lr = l & 15, lq = l >> 4;
    const int row0 = blockIdx.x * 128;
    f32x4 acc[2][NT] = {};
    const u16* Ab = (const u16*)Ap_;
    const float* Af = (const float*)Ap_;

    for (int kc = 0; kc < K / BK; ++kc) {
        #pragma unroll
        for (int i = 0; i < 4; ++i) {
            int f = (i * 256 + tid) * 16;
            int row = f >> 7, cb = f & 127;
            int ce = cb >> 1;
            int gr = row0 + row; if (gr >= M) gr = M - 1;
            if (AF32) {
                const float* s = &Af[(size_t)gr * K + kc * BK + ce];
                float4 v0 = *reinterpret_cast<const float4*>(s);
                float4 v1 = *reinterpret_cast<const float4*>(s + 4);
                ushort4 t0, t1;
                t0.x = f2b(v0.x); t0.y = f2b(v0.y); t0.z = f2b(v0.z); t0.w = f2b(v0.w);
                t1.x = f2b(v1.x); t1.y = f2b(v1.y); t1.z = f2b(v1.z); t1.w = f2b(v1.w);
                *reinterpret_cast<ushort4*>(&lA[row * ST + ce]) = t0;
                *reinterpret_cast<ushort4*>(&lA[row * ST + ce + 4]) = t1;
            } else {
                float4 v = *reinterpret_cast<const float4*>(&Ab[(size_t)gr * K + kc * BK + ce]);
                *reinterpret_cast<float4*>(&lA[row * ST + ce]) = v;
            }
        }
        #pragma unroll
        for (int i = 0; i < (NB * 128 + 4095) / 4096; ++i) {
            int f = (i * 256 + tid) * 16;
            if (f < NB * 128) {
                int row = f >> 7, ce = (f & 127) >> 1;
                float4 v = *reinterpret_cast<const float4*>(&Wt[(size_t)row * K + kc * BK + ce]);
                *reinterpret_cast<float4*>(&lB[row * ST + ce]) = v;
            }
        }
        __syncthreads();
        #pragma unroll
        for (int ks = 0; ks < 2; ++ks) {
            const int kk = ks * 32 + lq * 8;
            bf16x8 aF[2], bF[NT];
            #pragma unroll
            for (int mr = 0; mr < 2; ++mr)
                aF[mr] = *reinterpret_cast<const bf16x8*>(&lA[(w * 32 + mr * 16 + lr) * ST + kk]);
            #pragma unroll
            for (int nr = 0; nr < NT; ++nr)
                bF[nr] = *reinterpret_cast<const bf16x8*>(&lB[(nr * 16 + lr) * ST + kk]);
            #pragma unroll
            for (int mr = 0; mr < 2; ++mr)
                #pragma unroll
                for (int nr = 0; nr < NT; ++nr)
                    acc[mr][nr] = __builtin_amdgcn_mfma_f32_16x16x32_bf16(aF[mr], bF[nr], acc[mr][nr], 0, 0, 0);
        }
        __syncthreads();
    }
    #pragma unroll
    for (int mr = 0; mr < 2; ++mr) {
        int rbase = row0 + w * 32 + mr * 16 + lq * 4;
        #pragma unroll
        for (int reg = 0; reg < 4; ++reg) {
            int gr = rbase + reg;
            if (gr < M) {
                #pragma unroll
                for (int nr = 0; nr < NT; ++nr) {
                    int gc = nr * 16 + lr;
                    if (gc < OUTW) {
                        float v = acc[mr][nr][reg];
                        if (OBF16)
                            ((u16*)Cp)[(size_t)gr * OUTW + gc] = f2b(v);
                        else
                            ((float*)Cp)[(size_t)gr * OUTW + gc] = v;
                    }
                }
            }
        }
    }
}

// ============================== el / er ==============================

__global__ __launch_bounds__(256) void elr4(const u16* __restrict__ h,
                                            const float* __restrict__ al,
                                            const float* __restrict__ ar,
                                            float* __restrict__ el, float* __restrict__ er, int N) {
    int wid = blockIdx.x * 4 + (threadIdx.x >> 6);
    int lane = threadIdx.x & 63;
    if (wid >= N) return;
    float h0 = b2f(h[(size_t)wid * 128 + lane]);
    float h1 = b2f(h[(size_t)wid * 128 + 64 + lane]);
    float pl0 = h0 * al[lane], pl1 = h1 * al[64 + lane];
    float pr0 = h0 * ar[lane], pr1 = h1 * ar[64 + lane];
    #pragma unroll
    for (int o = 16; o >= 1; o >>= 1) {
        pl0 += __shfl_xor(pl0, o); pl1 += __shfl_xor(pl1, o);
        pr0 += __shfl_xor(pr0, o); pr1 += __shfl_xor(pr1, o);
    }
    if ((lane & 31) == 0) {
        int hd = lane >> 5;
        el[wid * 4 + hd]     = pl0;
        el[wid * 4 + 2 + hd] = pl1;
        er[wid * 4 + hd]     = pr0;
        er[wid * 4 + 2 + hd] = pr1;
    }
}

__global__ __launch_bounds__(256) void elr1(const u16* __restrict__ h,
                                            const float* __restrict__ al,
                                            const float* __restrict__ ar,
                                            float* __restrict__ el, float* __restrict__ er, int N) {
    int wid = blockIdx.x * 4 + (threadIdx.x >> 6);
    int lane = threadIdx.x & 63;
    if (wid >= N) return;
    float hv = (lane < 40) ? b2f(h[(size_t)wid * 40 + lane]) : 0.f;
    float pl = (lane < 40) ? hv * al[lane] : 0.f;
    float pr = (lane < 40) ? hv * ar[lane] : 0.f;
    #pragma unroll
    for (int o = 32; o >= 1; o >>= 1) { pl += __shfl_xor(pl, o); pr += __shfl_xor(pr, o); }
    if (lane == 0) { el[wid] = pl; er[wid] = pr; }
}

// ============================== edge softmax weights ==============================

// thread per (node, head): unnormalized alpha into ew[p*4+hh], 1/sum into invs[node*4+hh]
__global__ __launch_bounds__(256) void ew4_kernel(const float* __restrict__ el,
                                                  const float* __restrict__ er,
                                                  const int* __restrict__ rowptr,
                                                  const int* __restrict__ csrc,
                                                  float* __restrict__ ew,
                                                  float* __restrict__ invs, int N) {
    int t = blockIdx.x * 256 + threadIdx.x;
    int node = t >> 2, hh = t & 3;
    if (node >= N) return;
    int beg = rowptr[node], end = rowptr[node + 1];
    float ern = er[node * 4 + hh];
    float m = -INFINITY;
    for (int p = beg; p < end; ++p) {
        float e = el[csrc[p] * 4 + hh] + ern; e = e > 0.f ? e : 0.2f * e;
        m = fmaxf(m, e);
    }
    float s = 0.f;
    for (int p = beg; p < end; ++p) {
        float e = el[csrc[p] * 4 + hh] + ern; e = e > 0.f ? e : 0.2f * e;
        float pe = __expf(e - m);
        s += pe;
        ew[p * 4 + hh] = pe;
    }
    invs[node * 4 + hh] = (end > beg) ? 1.f / s : 0.f;
}

// thread per node, single head
__global__ __launch_bounds__(256) void ew1_kernel(const float* __restrict__ el,
                                                  const float* __restrict__ er,
                                                  const int* __restrict__ rowptr,
                                                  const int* __restrict__ csrc,
                                                  float* __restrict__ ew,
                                                  float* __restrict__ invs, int N) {
    int node = blockIdx.x * 256 + threadIdx.x;
    if (node >= N) return;
    int beg = rowptr[node], end = rowptr[node + 1];
    float ern = er[node];
    float m = -INFINITY;
    for (int p = beg; p < end; ++p) {
        float e = el[csrc[p]] + ern; e = e > 0.f ? e : 0.2f * e;
        m = fmaxf(m, e);
    }
    float s = 0.f;
    for (int p = beg; p < end; ++p) {
        float e = el[csrc[p]] + ern; e = e > 0.f ? e : 0.2f * e;
        float pe = __expf(e - m);
        s += pe;
        ew[p] = pe;
    }
    invs[node] = (end > beg) ? 1.f / s : 0.f;
}

// ============================== aggregation (pure gather-FMA) ==============================

template<bool RELU>
__global__ __launch_bounds__(256) void agg4v3(const u32* __restrict__ h,   // [N][64] dwords
                                              const float* __restrict__ ewf,
                                              const float* __restrict__ invs,
                                              const float* __restrict__ bias,
                                              const int* __restrict__ rowptr,
                                              const int* __restrict__ csrc,
                                              u32* __restrict__ out, int N) {
    const int wslot = threadIdx.x >> 6, lane = threadIdx.x & 63;
    const int wid = blockIdx.x * 4 + wslot;
    if (wid >= N) return;
    const int beg = __builtin_amdgcn_readfirstlane(rowptr[wid]);
    const int end = __builtin_amdgcn_readfirstlane(rowptr[wid + 1]);
    const int hh = lane >> 4;
    const float iv = invs[wid * 4 + hh];
    const float2 bv = reinterpret_cast<const float2*>(bias)[lane];

    float a[8] = {}, b[8] = {};
    int p = beg;
    for (; p + 8 <= end; p += 8) {
        int sid[8]; u32 hv[8]; float wg[8];
        #pragma unroll
        for (int k = 0; k < 8; ++k) sid[k] = csrc[p + k];
        #pragma unroll
        for (int k = 0; k < 8; ++k) hv[k] = h[(size_t)sid[k] * 64 + lane];
        #pragma unroll
        for (int k = 0; k < 8; ++k) wg[k] = ewf[(p + k) * 4 + hh];
        #pragma unroll
        for (int k = 0; k < 8; ++k) {
            a[k] = fmaf(wg[k], bflo(hv[k]), a[k]);
            b[k] = fmaf(wg[k], bfhi(hv[k]), b[k]);
        }
    }
    for (; p < end; ++p) {
        int sid = csrc[p];
        float wg = ewf[p * 4 + hh];
        u32 hv = h[(size_t)sid * 64 + lane];
        a[0] = fmaf(wg, bflo(hv), a[0]);
        b[0] = fmaf(wg, bfhi(hv), b[0]);
    }
    float accA = ((a[0] + a[1]) + (a[2] + a[3])) + ((a[4] + a[5]) + (a[6] + a[7]));
    float accB = ((b[0] + b[1]) + (b[2] + b[3])) + ((b[4] + b[5]) + (b[6] + b[7]));
    float oA = accA * iv + bv.x;
    float oB = accB * iv + bv.y;
    if (RELU) { oA = fmaxf(oA, 0.f); oB = fmaxf(oB, 0.f); }
    out[(size_t)wid * 64 + lane] = ((u32)f2b(oB) << 16) | (u32)f2b(oA);
}

// single-head aggregation + bias + log_softmax(40); h [N,40] bf16, out fp32
__global__ __launch_bounds__(256) void agg1v3(const u16* __restrict__ h,
                                              const float* __restrict__ ew,
                                              const float* __restrict__ invs,
                                              const float* __restrict__ bias,
                                              const int* __restrict__ rowptr,
                                              const int* __restrict__ csrc,
                                              float* __restrict__ out, int N) {
    const int wslot = threadIdx.x >> 6, lane = threadIdx.x & 63;
    const int wid = blockIdx.x * 4 + wslot;
    if (wid >= N) return;
    const int beg = __builtin_amdgcn_readfirstlane(rowptr[wid]);
    const int end = __builtin_amdgcn_readfirstlane(rowptr[wid + 1]);
    const int ll = lane < 40 ? lane : 39;   // clamp: same cache line
    const float iv = invs[wid];

    float a[8] = {};
    int p = beg;
    for (; p + 8 <= end; p += 8) {
        int sid[8]; float x[8], wg[8];
        #pragma unroll
        for (int k = 0; k < 8; ++k) sid[k] = csrc[p + k];
        #pragma unroll
        for (int k = 0; k < 8; ++k) x[k] = b2f(h[(size_t)sid[k] * 40 + ll]);
        #pragma unroll
        for (int k = 0; k < 8; ++k) wg[k] = ew[p + k];
        #pragma unroll
        for (int k = 0; k < 8; ++k) a[k] = fmaf(wg[k], x[k], a[k]);
    }
    for (; p < end; ++p) {
        a[0] = fmaf(ew[p], b2f(h[(size_t)csrc[p] * 40 + ll]), a[0]);
    }
    float acc = ((a[0] + a[1]) + (a[2] + a[3])) + ((a[4] + a[5]) + (a[6] + a[7]));
    float v = acc * iv + ((lane < 40) ? bias[lane] : 0.f);
    float vv = (lane < 40) ? v : -INFINITY;
    float mx = vv;
    #pragma unroll
    for (int o = 32; o >= 1; o >>= 1) mx = fmaxf(mx, __shfl_xor(mx, o));
    float ex = (lane < 40) ? __expf(v - mx) : 0.f;
    float se = ex;
    #pragma unroll
    for (int o = 32; o >= 1; o >>= 1) se += __shfl_xor(se, o);
    if (lane < 40) out[(size_t)wid * 40 + lane] = v - mx - logf(se);
}

// ============================== launch ==============================

extern "C" void kernel_launch(void* const* d_in, const int* in_sizes, int n_in,
                              void* d_out, int out_size, void* d_ws, size_t ws_size,
                              hipStream_t stream) {
    const float* feat = (const float*)d_in[0];
    const float* W1  = (const float*)d_in[1];
    const float* al1 = (const float*)d_in[2];
    const float* ar1 = (const float*)d_in[3];
    const float* b1  = (const float*)d_in[4];
    const float* W2  = (const float*)d_in[5];
    const float* al2 = (const float*)d_in[6];
    const float* ar2 = (const float*)d_in[7];
    const float* b2  = (const float*)d_in[8];
    const float* W3  = (const float*)d_in[9];
    const float* al3 = (const float*)d_in[10];
    const float* ar3 = (const float*)d_in[11];
    const float* b3  = (const float*)d_in[12];
    const int*   src = (const int*)d_in[13];
    const int*   dst = (const int*)d_in[14];
    float* out = (float*)d_out;
    const int N = NN, E = NE;

    char* ws = (char*)d_ws;
    size_t off = 0;
    auto alloc = [&](size_t bytes) -> char* {
        char* p = ws + off;
        off += (bytes + 255) & ~(size_t)255;
        return p;
    };
    int* deg    = (int*)alloc((size_t)N * 4);
    int* rowptr = (int*)alloc((size_t)(N + 1) * 4);
    int* bsum   = (int*)alloc(512 * 4);
    int* csrc   = (int*)alloc((size_t)E * 4);
    float* el   = (float*)alloc((size_t)N * 4 * 4);
    float* er   = (float*)alloc((size_t)N * 4 * 4);
    float* ew   = (float*)alloc((size_t)E * 4 * 4);   // edge softmax weights (4 heads)
    float* invs = (float*)alloc((size_t)N * 4 * 4);   // per (node,head) 1/sum
    u16* hb     = (u16*)alloc((size_t)N * 128 * 2);
    u16* xb     = (u16*)alloc((size_t)N * 128 * 2);
    u16* h3     = (u16*)alloc((size_t)N * 40 * 2 + 256);
    u16* W1t    = (u16*)alloc((size_t)128 * 256 * 2);
    u16* W2t    = (u16*)alloc((size_t)128 * 128 * 2);
    u16* W3t    = (u16*)alloc((size_t)48 * 128 * 2);

    // ---- CSR build ----
    hipMemsetAsync(deg, 0, (size_t)N * 4, stream);
    hist_kernel<<<(E + 255) / 256, 256, 0, stream>>>(dst, deg, E);
    int NB = (N + 255) / 256;
    scan_local<<<NB, 256, 0, stream>>>(deg, rowptr, bsum, N);
    scan_bsum<<<1, 512, 0, stream>>>(bsum, NB);
    scan_add<<<(N + 255) / 256, 256, 0, stream>>>(rowptr, bsum, N);
    hipMemsetAsync(deg, 0, (size_t)N * 4, stream);
    scatter_kernel<<<(E + 255) / 256, 256, 0, stream>>>(src, dst, rowptr, deg, csrc, E);

    // ---- weight prep ----
    transW<<<(128 * 256 + 255) / 256, 256, 0, stream>>>(W1, W1t, 256, 128, 128);
    transW<<<(128 * 128 + 255) / 256, 256, 0, stream>>>(W2, W2t, 128, 128, 128);
    transW<<<(48 * 128 + 255) / 256, 256, 0, stream>>>(W3, W3t, 128, 40, 48);

    int gemmGrid = (N + 127) / 128;
    int nodeGrid = (N + 3) / 4;
    int ew4Grid  = (N * 4 + 255) / 256;
    int ew1Grid  = (N + 255) / 256;

    // ---- layer 1 ----
    gemm_mfma<256, 8, 128, true, true><<<gemmGrid, 256, 0, stream>>>(feat, W1t, hb, N);
    elr4<<<nodeGrid, 256, 0, stream>>>(hb, al1, ar1, el, er, N);
    ew4_kernel<<<ew4Grid, 256, 0, stream>>>(el, er, rowptr, csrc, ew, invs, N);
    agg4v3<true><<<nodeGrid, 256, 0, stream>>>((const u32*)hb, ew, invs, b1, rowptr, csrc,
                                               (u32*)xb, N);

    // ---- layer 2 ----
    gemm_mfma<128, 8, 128, true, false><<<gemmGrid, 256, 0, stream>>>(xb, W2t, hb, N);
    elr4<<<nodeGrid, 256, 0, stream>>>(hb, al2, ar2, el, er, N);
    ew4_kernel<<<ew4Grid, 256, 0, stream>>>(el, er, rowptr, csrc, ew, invs, N);
    agg4v3<true><<<nodeGrid, 256, 0, stream>>>((const u32*)hb, ew, invs, b2, rowptr, csrc,
                                               (u32*)xb, N);

    // ---- layer 3 (+ fused log_softmax) ----
    gemm_mfma<128, 3, 40, true, false><<<gemmGrid, 256, 0, stream>>>(xb, W3t, h3, N);
    elr1<<<nodeGrid, 256, 0, stream>>>(h3, al3, ar3, el, er, N);
    ew1_kernel<<<ew1Grid, 256, 0, stream>>>(el, er, rowptr, csrc, ew, invs, N);
    agg1v3<<<nodeGrid, 256, 0, stream>>>(h3, ew, invs, b3, rowptr, csrc, out, N);
}

// Round 6
// 399.461 us; speedup vs baseline: 1.1513x; 1.1513x over previous
//
#include <hip/hip_runtime.h>
#include <hip/hip_bf16.h>
#include <math.h>

#define NN 100000
#define NE 1000000
#define CAP 128
#define NPB 512                          // nodes per bucket (pow2, shift 9)
#define NBUC ((NN + NPB - 1) / NPB)      // 196
#define CAPB 8192                        // max staged edges per bucket
#define P1E ((NE + 255) / 256)           // 3907 edges per part1 block

typedef __attribute__((ext_vector_type(8))) short bf16x8;
typedef __attribute__((ext_vector_type(4))) float f32x4;
typedef unsigned int u32;
typedef unsigned short u16;
typedef unsigned long long u64;

__device__ __forceinline__ u16 f2b(float f) {
    __hip_bfloat16 h = __float2bfloat16(f);
    return *reinterpret_cast<u16*>(&h);
}
__device__ __forceinline__ float b2f(u16 u) {
    __hip_bfloat16 h = *reinterpret_cast<__hip_bfloat16*>(&u);
    return __bfloat162float(h);
}
__device__ __forceinline__ float bflo(u32 v) { return __uint_as_float(v << 16); }
__device__ __forceinline__ float bfhi(u32 v) { return __uint_as_float(v & 0xffff0000u); }

// ============================== CSR: degree + rowptr ==============================

__global__ void hist_kernel(const int* __restrict__ dst, int* __restrict__ deg, int E) {
    int i = blockIdx.x * blockDim.x + threadIdx.x;
    if (i < E) atomicAdd(&deg[dst[i]], 1);
}

__global__ void scan_local(const int* __restrict__ deg, int* __restrict__ rowptr,
                           int* __restrict__ bsum, int N) {
    __shared__ int s[256];
    int i = blockIdx.x * 256 + threadIdx.x;
    int v = (i < N) ? deg[i] : 0;
    s[threadIdx.x] = v;
    __syncthreads();
    #pragma unroll
    for (int off = 1; off < 256; off <<= 1) {
        int t = (threadIdx.x >= off) ? s[threadIdx.x - off] : 0;
        __syncthreads();
        s[threadIdx.x] += t;
        __syncthreads();
    }
    if (i < N) rowptr[i + 1] = s[threadIdx.x];
    if (threadIdx.x == 255) bsum[blockIdx.x] = s[255];
}

__global__ void scan_bsum(int* __restrict__ bsum, int NB) {
    __shared__ int s[512];
    int v = (threadIdx.x < NB) ? bsum[threadIdx.x] : 0;
    s[threadIdx.x] = v;
    __syncthreads();
    for (int off = 1; off < 512; off <<= 1) {
        int t = (threadIdx.x >= off) ? s[threadIdx.x - off] : 0;
        __syncthreads();
        s[threadIdx.x] += t;
        __syncthreads();
    }
    if (threadIdx.x < NB) bsum[threadIdx.x] = s[threadIdx.x] - v;  // exclusive
}

__global__ void scan_add(int* __restrict__ rowptr, const int* __restrict__ bsum, int N) {
    int i = blockIdx.x * blockDim.x + threadIdx.x;
    if (i < N) rowptr[i + 1] += bsum[i >> 8];
    if (i == 0) rowptr[0] = 0;
}

// ============================== CSR: bucketed edge partition ==============================

__global__ void initcur(const int* __restrict__ rowptr, int* __restrict__ gcur) {
    int b = threadIdx.x;
    if (b < NBUC) gcur[b] = rowptr[b << 9];
}

// pass 1: partition edges into dst-buckets (coalesced writes of (dst,src) pairs)
__global__ __launch_bounds__(256) void part1(const int* __restrict__ src,
                                             const int* __restrict__ dst,
                                             int* __restrict__ gcur,
                                             long long* __restrict__ ebuf) {
    __shared__ int cnt[256], sex[256], base[256], cur2[256], scn[256];
    __shared__ long long stage[P1E];
    const int tid = threadIdx.x;
    const int e0 = blockIdx.x * P1E;
    const int e1 = min(e0 + P1E, NE);
    cnt[tid] = 0;
    __syncthreads();
    for (int i = e0 + tid; i < e1; i += 256)
        atomicAdd(&cnt[dst[i] >> 9], 1);
    __syncthreads();
    int v = cnt[tid];
    scn[tid] = v;
    __syncthreads();
    #pragma unroll
    for (int off = 1; off < 256; off <<= 1) {
        int t = (tid >= off) ? scn[tid - off] : 0;
        __syncthreads();
        scn[tid] += t;
        __syncthreads();
    }
    sex[tid] = scn[tid] - v;  // exclusive scan
    if (tid < NBUC) base[tid] = (v > 0) ? atomicAdd(&gcur[tid], v) : 0;
    cur2[tid] = 0;
    __syncthreads();
    for (int i = e0 + tid; i < e1; i += 256) {
        int d = dst[i], s = src[i];
        int b = d >> 9;
        int slot = sex[b] + atomicAdd(&cur2[b], 1);
        stage[slot] = ((long long)(u32)d << 32) | (u32)s;
    }
    __syncthreads();
    const int tot = e1 - e0;
    for (int i = tid; i < tot; i += 256) {
        long long ll = stage[i];
        int b = (int)((u64)ll >> 32) >> 9;
        ebuf[(size_t)base[b] + (i - sex[b])] = ll;
    }
}

// pass 2: per-bucket scatter (LDS-staged, coalesced csrc writes)
__global__ __launch_bounds__(256) void part2(const int* __restrict__ rowptr,
                                             const long long* __restrict__ ebuf,
                                             int* __restrict__ csrc) {
    __shared__ int nb[NPB], cnt[NPB];
    __shared__ int stage[CAPB];
    const int tid = threadIdx.x;
    const int n0 = blockIdx.x << 9;
    const int nn = min(NPB, NN - n0);
    const int estart = rowptr[n0];
    const int eend = rowptr[n0 + nn];
    const int tot = eend - estart;
    for (int i = tid; i < nn; i += 256) {
        nb[i] = rowptr[n0 + i] - estart;
        cnt[i] = 0;
    }
    __syncthreads();
    if (tot <= CAPB) {
        for (int i = estart + tid; i < eend; i += 256) {
            long long ll = ebuf[i];
            int ln = (int)((u64)ll >> 32) - n0;
            int pos = nb[ln] + atomicAdd(&cnt[ln], 1);
            stage[pos] = (int)ll;
        }
        __syncthreads();
        for (int i = tid; i < tot; i += 256) csrc[estart + i] = stage[i];
    } else {  // improbable fallback
        for (int i = estart + tid; i < eend; i += 256) {
            long long ll = ebuf[i];
            int ln = (int)((u64)ll >> 32) - n0;
            int pos = nb[ln] + atomicAdd(&cnt[ln], 1);
            csrc[estart + pos] = (int)ll;
        }
    }
}

// ============================== weight prep ==============================

__global__ void transW(const float* __restrict__ W, u16* __restrict__ Wt,
                       int K, int Nin, int NBpad) {
    int idx = blockIdx.x * 256 + threadIdx.x;
    if (idx < NBpad * K) {
        int n = idx / K, k = idx % K;
        float v = (n < Nin) ? W[(size_t)k * Nin + n] : 0.f;
        Wt[idx] = f2b(v);
    }
}

// ============================== MFMA GEMM + fused el/er ==============================
// C[M,OUTW](bf16) = A[M,K] * Wt[NT*16,K]^T; BM=64, 4 waves, wave = 16 rows x full width.
// Register-prefetched staging; epilogue computes el/er = (C*al).sum / (C*ar).sum per head.
template<int K, int NT, int OUTW, bool AF32, int NH>
__global__ __launch_bounds__(256) void gemm_elr(const void* __restrict__ Ap_,
                                                const u16* __restrict__ Wt,
                                                const float* __restrict__ al,
                                                const float* __restrict__ ar,
                                                u16* __restrict__ C,
                                                float* __restrict__ el,
                                                float* __restrict__ er, int M) {
    constexpr int BK = 64;
    constexpr int ST = 72;                       // 144 B stride (16-B aligned)
    constexpr int NB = NT * 16;
    constexpr int NK = K / BK;
    constexpr int CB = (NB * 128 + 4095) / 4096; // B 16-B chunks per thread
    __shared__ u16 lA[64 * ST];
    __shared__ u16 lB[NB * ST];
    const int tid = threadIdx.x;
    const int w = tid >> 6, l = tid & 63;
    const int lr = l & 15, lq = l >> 4;
    const int row0 = blockIdx.x * 64;
    f32x4 acc[NT] = {};
    const u16* Ab = (const u16*)Ap_;
    const float* Af = (const float*)Ap_;

    float4 pa[AF32 ? 4 : 2];
    float4 pb[CB];

    auto loadA = [&](int kc) {
        #pragma unroll
        for (int i = 0; i < 2; ++i) {
            int f = (i * 256 + tid) * 16;
            int row = f >> 7, ce = (f & 127) >> 1;
            int gr = row0 + row; if (gr >= M) gr = M - 1;
            if (AF32) {
                const float* s = &Af[(size_t)gr * K + kc * BK + ce];
                pa[2 * i]     = *reinterpret_cast<const float4*>(s);
                pa[2 * i + 1] = *reinterpret_cast<const float4*>(s + 4);
            } else {
                pa[i] = *reinterpret_cast<const float4*>(&Ab[(size_t)gr * K + kc * BK + ce]);
            }
        }
    };
    auto loadB = [&](int kc) {
        #pragma unroll
        for (int i = 0; i < CB; ++i) {
            int f = (i * 256 + tid) * 16;
            if (f < NB * 128) {
                int row = f >> 7, ce = (f & 127) >> 1;
                pb[i] = *reinterpret_cast<const float4*>(&Wt[(size_t)row * K + kc * BK + ce]);
            }
        }
    };
    auto storeA = [&]() {
        #pragma unroll
        for (int i = 0; i < 2; ++i) {
            int f = (i * 256 + tid) * 16;
            int row = f >> 7, ce = (f & 127) >> 1;
            if (AF32) {
                const float* v0 = reinterpret_cast<const float*>(&pa[2 * i]);
                const float* v1 = reinterpret_cast<const float*>(&pa[2 * i + 1]);
                ushort4 t0, t1;
                t0.x = f2b(v0[0]); t0.y = f2b(v0[1]); t0.z = f2b(v0[2]); t0.w = f2b(v0[3]);
                t1.x = f2b(v1[0]); t1.y = f2b(v1[1]); t1.z = f2b(v1[2]); t1.w = f2b(v1[3]);
                *reinterpret_cast<ushort4*>(&lA[row * ST + ce])     = t0;
                *reinterpret_cast<ushort4*>(&lA[row * ST + ce + 4]) = t1;
            } else {
                *reinterpret_cast<float4*>(&lA[row * ST + ce]) = pa[i];
            }
        }
    };
    auto storeB = [&]() {
        #pragma unroll
        for (int i = 0; i < CB; ++i) {
            int f = (i * 256 + tid) * 16;
            if (f < NB * 128) {
                int row = f >> 7, ce = (f & 127) >> 1;
                *reinterpret_cast<float4*>(&lB[row * ST + ce]) = pb[i];
            }
        }
    };

    loadA(0); loadB(0);
    storeA(); storeB();
    __syncthreads();
    for (int kc = 0; kc < NK; ++kc) {
        const bool more = (kc + 1 < NK);
        if (more) { loadA(kc + 1); loadB(kc + 1); }   // issue early, hide under compute
        #pragma unroll
        for (int ks = 0; ks < 2; ++ks) {
            const int kk = ks * 32 + lq * 8;
            bf16x8 aF = *reinterpret_cast<const bf16x8*>(&lA[(w * 16 + lr) * ST + kk]);
            bf16x8 bF[NT];
            #pragma unroll
            for (int nr = 0; nr < NT; ++nr)
                bF[nr] = *reinterpret_cast<const bf16x8*>(&lB[(nr * 16 + lr) * ST + kk]);
            #pragma unroll
            for (int nr = 0; nr < NT; ++nr)
                acc[nr] = __builtin_amdgcn_mfma_f32_16x16x32_bf16(aF, bF[nr], acc[nr], 0, 0, 0);
        }
        __syncthreads();
        if (more) { storeA(); storeB(); __syncthreads(); }
    }

    // epilogue: C store (bf16) + fused el/er (C/D layout: col=lr, row=lq*4+reg [m89])
    float alv[NT], arv[NT];
    #pragma unroll
    for (int nr = 0; nr < NT; ++nr) {
        int c = nr * 16 + lr;
        alv[nr] = (c < OUTW) ? al[c] : 0.f;
        arv[nr] = (c < OUTW) ? ar[c] : 0.f;
    }
    #pragma unroll
    for (int reg = 0; reg < 4; ++reg) {
        int gr = row0 + w * 16 + lq * 4 + reg;
        bool ok = gr < M;
        if (ok) {
            #pragma unroll
            for (int nr = 0; nr < NT; ++nr) {
                int gc = nr * 16 + lr;
                if (gc < OUTW) C[(size_t)gr * OUTW + gc] = f2b(acc[nr][reg]);
            }
        }
        float pl[NH] = {}, pr[NH] = {};
        #pragma unroll
        for (int nr = 0; nr < NT; ++nr) {
            int hidx = (NH == 1) ? 0 : (nr >> 1);
            pl[hidx] = fmaf(acc[nr][reg], alv[nr], pl[hidx]);
            pr[hidx] = fmaf(acc[nr][reg], arv[nr], pr[hidx]);
        }
        #pragma unroll
        for (int o = 8; o >= 1; o >>= 1) {
            #pragma unroll
            for (int hh = 0; hh < NH; ++hh) {
                pl[hh] += __shfl_xor(pl[hh], o);
                pr[hh] += __shfl_xor(pr[hh], o);
            }
        }
        if (ok && lr == 0) {
            #pragma unroll
            for (int hh = 0; hh < NH; ++hh) {
                el[gr * NH + hh] = pl[hh];
                er[gr * NH + hh] = pr[hh];
            }
        }
    }
}

// ============================== aggregation (fused, no-max softmax) ==============================
// Safe without max-subtraction: e = leaky_relu(el+er) ~ O(10) << 88, exp cannot overflow.

template<bool RELU>
__global__ __launch_bounds__(256) void agg4v4(const u32* __restrict__ h,   // [N][64] dwords
                                              const float4* __restrict__ el4,
                                              const float4* __restrict__ er4,
                                              const float* __restrict__ bias,
                                              const int* __restrict__ rowptr,
                                              const int* __restrict__ csrc,
                                              u32* __restrict__ out, int N) {
    __shared__ float4 s_ew[4][CAP];
    __shared__ int s_sid[4][CAP];
    const int wslot = threadIdx.x >> 6, lane = threadIdx.x & 63;
    const int wid = blockIdx.x * 4 + wslot;
    if (wid >= N) return;
    const int beg = rowptr[wid];
    const int deg = rowptr[wid + 1] - beg;
    const float4 er = er4[wid];
    const int hh = lane >> 4;
    const float2 bv = reinterpret_cast<const float2*>(bias)[lane];
    float accA = 0.f, accB = 0.f, invs;

    if (deg <= CAP) {
        float s0 = 0.f, s1 = 0.f, s2 = 0.f, s3 = 0.f;
        for (int base = 0; base < deg; base += 64) {
            int j = base + lane;
            if (j < deg) {
                int sid = csrc[beg + j];
                float4 ev = el4[sid];
                float e0 = ev.x + er.x; e0 = e0 > 0.f ? e0 : 0.2f * e0;
                float e1 = ev.y + er.y; e1 = e1 > 0.f ? e1 : 0.2f * e1;
                float e2 = ev.z + er.z; e2 = e2 > 0.f ? e2 : 0.2f * e2;
                float e3 = ev.w + er.w; e3 = e3 > 0.f ? e3 : 0.2f * e3;
                float p0 = __expf(e0), p1 = __expf(e1), p2 = __expf(e2), p3 = __expf(e3);
                s_sid[wslot][j] = sid;
                s_ew[wslot][j] = make_float4(p0, p1, p2, p3);
                s0 += p0; s1 += p1; s2 += p2; s3 += p3;
            }
        }
        #pragma unroll
        for (int o = 32; o >= 1; o >>= 1) {
            s0 += __shfl_xor(s0, o); s1 += __shfl_xor(s1, o);
            s2 += __shfl_xor(s2, o); s3 += __shfl_xor(s3, o);
        }
        float sh = hh == 0 ? s0 : hh == 1 ? s1 : hh == 2 ? s2 : s3;
        invs = (deg > 0) ? 1.f / sh : 0.f;
        const float* ewf = reinterpret_cast<const float*>(&s_ew[wslot][0]);
        const int* sidp = &s_sid[wslot][0];
        float a[8] = {}, b[8] = {};
        int p = 0;
        const int deg8 = deg & ~7;
        for (; p < deg8; p += 8) {
            int sid[8]; u32 hv[8]; float wg[8];
            #pragma unroll
            for (int k = 0; k < 8; ++k) sid[k] = sidp[p + k];
            #pragma unroll
            for (int k = 0; k < 8; ++k) hv[k] = h[(size_t)sid[k] * 64 + lane];
            #pragma unroll
            for (int k = 0; k < 8; ++k) wg[k] = ewf[(p + k) * 4 + hh];
            #pragma unroll
            for (int k = 0; k < 8; ++k) {
                a[k] = fmaf(wg[k], bflo(hv[k]), a[k]);
                b[k] = fmaf(wg[k], bfhi(hv[k]), b[k]);
            }
        }
        for (; p < deg; ++p) {
            int sid = sidp[p];
            float wg = ewf[p * 4 + hh];
            u32 hv = h[(size_t)sid * 64 + lane];
            a[0] = fmaf(wg, bflo(hv), a[0]);
            b[0] = fmaf(wg, bfhi(hv), b[0]);
        }
        accA = ((a[0] + a[1]) + (a[2] + a[3])) + ((a[4] + a[5]) + (a[6] + a[7]));
        accB = ((b[0] + b[1]) + (b[2] + b[3])) + ((b[4] + b[5]) + (b[6] + b[7]));
    } else {
        float er_h = hh == 0 ? er.x : hh == 1 ? er.y : hh == 2 ? er.z : er.w;
        float s = 0.f;
        for (int q = beg; q < beg + deg; ++q) {
            int sid = csrc[q];
            float4 ev = el4[sid];
            float e = (hh == 0 ? ev.x : hh == 1 ? ev.y : hh == 2 ? ev.z : ev.w) + er_h;
            e = e > 0.f ? e : 0.2f * e;
            float pe = __expf(e);
            u32 hv = h[(size_t)sid * 64 + lane];
            s += pe;
            accA = fmaf(pe, bflo(hv), accA);
            accB = fmaf(pe, bfhi(hv), accB);
        }
        invs = 1.f / s;
    }
    float oA = accA * invs + bv.x;
    float oB = accB * invs + bv.y;
    if (RELU) { oA = fmaxf(oA, 0.f); oB = fmaxf(oB, 0.f); }
    out[(size_t)wid * 64 + lane] = ((u32)f2b(oB) << 16) | (u32)f2b(oA);
}

// single head + bias + log_softmax(40); h [N,40] bf16, out fp32
__global__ __launch_bounds__(256) void agg1v4(const u16* __restrict__ h,
                                              const float* __restrict__ el,
                                              const float* __restrict__ er,
                                              const float* __restrict__ bias,
                                              const int* __restrict__ rowptr,
                                              const int* __restrict__ csrc,
                                              float* __restrict__ out, int N) {
    __shared__ float s_ew[4][CAP];
    __shared__ int s_sid[4][CAP];
    const int wslot = threadIdx.x >> 6, lane = threadIdx.x & 63;
    const int wid = blockIdx.x * 4 + wslot;
    if (wid >= N) return;
    const int beg = rowptr[wid];
    const int deg = rowptr[wid + 1] - beg;
    const float ern = er[wid];
    const int ll = lane < 40 ? lane : 39;
    float acc = 0.f, invs;

    if (deg <= CAP) {
        float s = 0.f;
        for (int base = 0; base < deg; base += 64) {
            int j = base + lane;
            if (j < deg) {
                int sid = csrc[beg + j];
                float e = el[sid] + ern; e = e > 0.f ? e : 0.2f * e;
                float pe = __expf(e);
                s_sid[wslot][j] = sid;
                s_ew[wslot][j] = pe;
                s += pe;
            }
        }
        #pragma unroll
        for (int o = 32; o >= 1; o >>= 1) s += __shfl_xor(s, o);
        invs = (deg > 0) ? 1.f / s : 0.f;
        float a[8] = {};
        int p = 0;
        const int deg8 = deg & ~7;
        for (; p < deg8; p += 8) {
            int sid[8]; float x[8], wg[8];
            #pragma unroll
            for (int k = 0; k < 8; ++k) sid[k] = s_sid[wslot][p + k];
            #pragma unroll
            for (int k = 0; k < 8; ++k) x[k] = b2f(h[(size_t)sid[k] * 40 + ll]);
            #pragma unroll
            for (int k = 0; k < 8; ++k) wg[k] = s_ew[wslot][p + k];
            #pragma unroll
            for (int k = 0; k < 8; ++k) a[k] = fmaf(wg[k], x[k], a[k]);
        }
        for (; p < deg; ++p)
            a[0] = fmaf(s_ew[wslot][p], b2f(h[(size_t)s_sid[wslot][p] * 40 + ll]), a[0]);
        acc = ((a[0] + a[1]) + (a[2] + a[3])) + ((a[4] + a[5]) + (a[6] + a[7]));
    } else {
        float s = 0.f;
        for (int q = beg; q < beg + deg; ++q) {
            int sid = csrc[q];
            float e = el[sid] + ern; e = e > 0.f ? e : 0.2f * e;
            float pe = __expf(e);
            s += pe;
            acc = fmaf(pe, b2f(h[(size_t)sid * 40 + ll]), acc);
        }
        invs = 1.f / s;
    }
    float v = acc * invs + ((lane < 40) ? bias[lane] : 0.f);
    float vv = (lane < 40) ? v : -INFINITY;
    float mx = vv;
    #pragma unroll
    for (int o = 32; o >= 1; o >>= 1) mx = fmaxf(mx, __shfl_xor(mx, o));
    float ex = (lane < 40) ? __expf(v - mx) : 0.f;
    float se = ex;
    #pragma unroll
    for (int o = 32; o >= 1; o >>= 1) se += __shfl_xor(se, o);
    if (lane < 40) out[(size_t)wid * 40 + lane] = v - mx - logf(se);
}

// ============================== launch ==============================

extern "C" void kernel_launch(void* const* d_in, const int* in_sizes, int n_in,
                              void* d_out, int out_size, void* d_ws, size_t ws_size,
                              hipStream_t stream) {
    const float* feat = (const float*)d_in[0];
    const float* W1  = (const float*)d_in[1];
    const float* al1 = (const float*)d_in[2];
    const float* ar1 = (const float*)d_in[3];
    const float* b1  = (const float*)d_in[4];
    const float* W2  = (const float*)d_in[5];
    const float* al2 = (const float*)d_in[6];
    const float* ar2 = (const float*)d_in[7];
    const float* b2  = (const float*)d_in[8];
    const float* W3  = (const float*)d_in[9];
    const float* al3 = (const float*)d_in[10];
    const float* ar3 = (const float*)d_in[11];
    const float* b3  = (const float*)d_in[12];
    const int*   src = (const int*)d_in[13];
    const int*   dst = (const int*)d_in[14];
    float* out = (float*)d_out;
    const int N = NN, E = NE;

    char* ws = (char*)d_ws;
    size_t off = 0;
    auto alloc = [&](size_t bytes) -> char* {
        char* p = ws + off;
        off += (bytes + 255) & ~(size_t)255;
        return p;
    };
    int* deg    = (int*)alloc((size_t)N * 4);
    int* rowptr = (int*)alloc((size_t)(N + 1) * 4);
    int* bsum   = (int*)alloc(512 * 4);
    int* gcur   = (int*)alloc(256 * 4);
    int* csrc   = (int*)alloc((size_t)E * 4);
    long long* ebuf = (long long*)alloc((size_t)E * 8);
    float* el   = (float*)alloc((size_t)N * 4 * 4);
    float* er   = (float*)alloc((size_t)N * 4 * 4);
    u16* hb     = (u16*)alloc((size_t)N * 128 * 2);
    u16* xb     = (u16*)alloc((size_t)N * 128 * 2);
    u16* h3     = (u16*)alloc((size_t)N * 40 * 2 + 256);
    u16* W1t    = (u16*)alloc((size_t)128 * 256 * 2);
    u16* W2t    = (u16*)alloc((size_t)128 * 128 * 2);
    u16* W3t    = (u16*)alloc((size_t)48 * 128 * 2);

    // ---- CSR rowptr ----
    hipMemsetAsync(deg, 0, (size_t)N * 4, stream);
    hist_kernel<<<(E + 255) / 256, 256, 0, stream>>>(dst, deg, E);
    int NB = (N + 255) / 256;
    scan_local<<<NB, 256, 0, stream>>>(deg, rowptr, bsum, N);
    scan_bsum<<<1, 512, 0, stream>>>(bsum, NB);
    scan_add<<<(N + 255) / 256, 256, 0, stream>>>(rowptr, bsum, N);
    // ---- bucketed edge partition -> csrc ----
    initcur<<<1, 256, 0, stream>>>(rowptr, gcur);
    part1<<<256, 256, 0, stream>>>(src, dst, gcur, ebuf);
    part2<<<NBUC, 256, 0, stream>>>(rowptr, ebuf, csrc);

    // ---- weight prep ----
    transW<<<(128 * 256 + 255) / 256, 256, 0, stream>>>(W1, W1t, 256, 128, 128);
    transW<<<(128 * 128 + 255) / 256, 256, 0, stream>>>(W2, W2t, 128, 128, 128);
    transW<<<(48 * 128 + 255) / 256, 256, 0, stream>>>(W3, W3t, 128, 40, 48);

    int gemmGrid = (N + 63) / 64;
    int nodeGrid = (N + 3) / 4;

    // ---- layer 1 ----
    gemm_elr<256, 8, 128, true, 4><<<gemmGrid, 256, 0, stream>>>(feat, W1t, al1, ar1, hb, el, er, N);
    agg4v4<true><<<nodeGrid, 256, 0, stream>>>((const u32*)hb, (const float4*)el, (const float4*)er,
                                               b1, rowptr, csrc, (u32*)xb, N);

    // ---- layer 2 ----
    gemm_elr<128, 8, 128, false, 4><<<gemmGrid, 256, 0, stream>>>(xb, W2t, al2, ar2, hb, el, er, N);
    agg4v4<true><<<nodeGrid, 256, 0, stream>>>((const u32*)hb, (const float4*)el, (const float4*)er,
                                               b2, rowptr, csrc, (u32*)xb, N);

    // ---- layer 3 (+ fused log_softmax) ----
    gemm_elr<128, 3, 40, false, 1><<<gemmGrid, 256, 0, stream>>>(xb, W3t, al3, ar3, h3, el, er, N);
    agg1v4<<<nodeGrid, 256, 0, stream>>>(h3, el, er, b3, rowptr, csrc, out, N);
}

// Round 7
// 358.667 us; speedup vs baseline: 1.2822x; 1.1137x over previous
//
#include <hip/hip_runtime.h>
#include <hip/hip_bf16.h>
#include <math.h>

#define NN 100000
#define NE 1000000
#define CAP 128
#define NPB 512                          // nodes per bucket (pow2, shift 9)
#define NBUC ((NN + NPB - 1) / NPB)      // 196
#define CAPB 8192                        // max staged edges per bucket
#define P1E ((NE + 255) / 256)           // 3907 edges per part1 block

typedef __attribute__((ext_vector_type(8))) short bf16x8;
typedef __attribute__((ext_vector_type(4))) float f32x4;
typedef unsigned int u32;
typedef unsigned short u16;
typedef unsigned long long u64;

__device__ __forceinline__ u16 f2b(float f) {
    __hip_bfloat16 h = __float2bfloat16(f);
    return *reinterpret_cast<u16*>(&h);
}
__device__ __forceinline__ float b2f(u16 u) {
    __hip_bfloat16 h = *reinterpret_cast<__hip_bfloat16*>(&u);
    return __bfloat162float(h);
}
__device__ __forceinline__ float bflo(u32 v) { return __uint_as_float(v << 16); }
__device__ __forceinline__ float bfhi(u32 v) { return __uint_as_float(v & 0xffff0000u); }

// ============================== CSR: degree + rowptr ==============================

__global__ void hist_kernel(const int* __restrict__ dst, int* __restrict__ deg, int E) {
    int i = blockIdx.x * blockDim.x + threadIdx.x;
    if (i < E) atomicAdd(&deg[dst[i]], 1);
}

__global__ void scan_local(const int* __restrict__ deg, int* __restrict__ rowptr,
                           int* __restrict__ bsum, int N) {
    __shared__ int s[256];
    int i = blockIdx.x * 256 + threadIdx.x;
    int v = (i < N) ? deg[i] : 0;
    s[threadIdx.x] = v;
    __syncthreads();
    #pragma unroll
    for (int off = 1; off < 256; off <<= 1) {
        int t = (threadIdx.x >= off) ? s[threadIdx.x - off] : 0;
        __syncthreads();
        s[threadIdx.x] += t;
        __syncthreads();
    }
    if (i < N) rowptr[i + 1] = s[threadIdx.x];
    if (threadIdx.x == 255) bsum[blockIdx.x] = s[255];
}

__global__ void scan_bsum(int* __restrict__ bsum, int NB) {
    __shared__ int s[512];
    int v = (threadIdx.x < NB) ? bsum[threadIdx.x] : 0;
    s[threadIdx.x] = v;
    __syncthreads();
    for (int off = 1; off < 512; off <<= 1) {
        int t = (threadIdx.x >= off) ? s[threadIdx.x - off] : 0;
        __syncthreads();
        s[threadIdx.x] += t;
        __syncthreads();
    }
    if (threadIdx.x < NB) bsum[threadIdx.x] = s[threadIdx.x] - v;  // exclusive
}

__global__ void scan_add(int* __restrict__ rowptr, const int* __restrict__ bsum, int N) {
    int i = blockIdx.x * blockDim.x + threadIdx.x;
    if (i < N) rowptr[i + 1] += bsum[i >> 8];
    if (i == 0) rowptr[0] = 0;
}

// ============================== CSR: bucketed edge partition ==============================

__global__ void initcur(const int* __restrict__ rowptr, int* __restrict__ gcur) {
    int b = threadIdx.x;
    if (b < NBUC) gcur[b] = rowptr[b << 9];
}

__global__ __launch_bounds__(256) void part1(const int* __restrict__ src,
                                             const int* __restrict__ dst,
                                             int* __restrict__ gcur,
                                             long long* __restrict__ ebuf) {
    __shared__ int cnt[256], sex[256], base[256], cur2[256], scn[256];
    __shared__ long long stage[P1E];
    const int tid = threadIdx.x;
    const int e0 = blockIdx.x * P1E;
    const int e1 = min(e0 + P1E, NE);
    cnt[tid] = 0;
    __syncthreads();
    for (int i = e0 + tid; i < e1; i += 256)
        atomicAdd(&cnt[dst[i] >> 9], 1);
    __syncthreads();
    int v = cnt[tid];
    scn[tid] = v;
    __syncthreads();
    #pragma unroll
    for (int off = 1; off < 256; off <<= 1) {
        int t = (tid >= off) ? scn[tid - off] : 0;
        __syncthreads();
        scn[tid] += t;
        __syncthreads();
    }
    sex[tid] = scn[tid] - v;  // exclusive scan
    if (tid < NBUC) base[tid] = (v > 0) ? atomicAdd(&gcur[tid], v) : 0;
    cur2[tid] = 0;
    __syncthreads();
    for (int i = e0 + tid; i < e1; i += 256) {
        int d = dst[i], s = src[i];
        int b = d >> 9;
        int slot = sex[b] + atomicAdd(&cur2[b], 1);
        stage[slot] = ((long long)(u32)d << 32) | (u32)s;
    }
    __syncthreads();
    const int tot = e1 - e0;
    for (int i = tid; i < tot; i += 256) {
        long long ll = stage[i];
        int b = (int)((u64)ll >> 32) >> 9;
        ebuf[(size_t)base[b] + (i - sex[b])] = ll;
    }
}

__global__ __launch_bounds__(256) void part2(const int* __restrict__ rowptr,
                                             const long long* __restrict__ ebuf,
                                             int* __restrict__ csrc) {
    __shared__ int nb[NPB], cnt[NPB];
    __shared__ int stage[CAPB];
    const int tid = threadIdx.x;
    const int n0 = blockIdx.x << 9;
    const int nn = min(NPB, NN - n0);
    const int estart = rowptr[n0];
    const int eend = rowptr[n0 + nn];
    const int tot = eend - estart;
    for (int i = tid; i < nn; i += 256) {
        nb[i] = rowptr[n0 + i] - estart;
        cnt[i] = 0;
    }
    __syncthreads();
    if (tot <= CAPB) {
        for (int i = estart + tid; i < eend; i += 256) {
            long long ll = ebuf[i];
            int ln = (int)((u64)ll >> 32) - n0;
            int pos = nb[ln] + atomicAdd(&cnt[ln], 1);
            stage[pos] = (int)ll;
        }
        __syncthreads();
        for (int i = tid; i < tot; i += 256) csrc[estart + i] = stage[i];
    } else {
        for (int i = estart + tid; i < eend; i += 256) {
            long long ll = ebuf[i];
            int ln = (int)((u64)ll >> 32) - n0;
            int pos = nb[ln] + atomicAdd(&cnt[ln], 1);
            csrc[estart + pos] = (int)ll;
        }
    }
}

// ============================== weight prep ==============================

__global__ void transW(const float* __restrict__ W, u16* __restrict__ Wt,
                       int K, int Nin, int NBpad) {
    int idx = blockIdx.x * 256 + threadIdx.x;
    if (idx < NBpad * K) {
        int n = idx / K, k = idx % K;
        float v = (n < Nin) ? W[(size_t)k * Nin + n] : 0.f;
        Wt[idx] = f2b(v);
    }
}

// ============================== MFMA GEMM: B-in-LDS, A direct-to-reg ==============================
// C[M,OUTW](bf16) = A[M,K] * Wt[NT*16,K]^T.  BM=128, 4 waves x 32 rows.
// B staged ONCE into LDS (XOR-swizzled 16B chunks, both sides), no barriers in K-loop.
// A fragments loaded straight global->reg (16B bf16 / 32B fp32+cvt per frag).
// Epilogue fuses el/er = (C*al).sum / (C*ar).sum per head.
template<int K, int NT, int OUTW, bool AF32, int NH>
__global__ __launch_bounds__(256) void gemm_breg(const void* __restrict__ Ap_,
                                                 const u16* __restrict__ Wt,
                                                 const float* __restrict__ al,
                                                 const float* __restrict__ ar,
                                                 u16* __restrict__ C,
                                                 float* __restrict__ el,
                                                 float* __restrict__ er, int M) {
    constexpr int NB = NT * 16;
    constexpr int NKS = K / 32;          // MFMA k-steps
    constexpr int CHK = K / 8;           // 16B chunks per B row
    __shared__ u16 lB[NB * K];           // chunk c of row stored at c^(row&7)
    const int tid = threadIdx.x;
    const int w = tid >> 6, l = tid & 63;
    const int lr = l & 15, lq = l >> 4;
    const u16* Ab = (const u16*)Ap_;
    const float* Af = (const float*)Ap_;

    // ---- stage B (coalesced read, swizzled LDS write) ----
    for (int idx = tid; idx < NB * CHK; idx += 256) {
        int row = idx / CHK, c = idx % CHK;
        float4 v = *reinterpret_cast<const float4*>(&Wt[(size_t)row * K + c * 8]);
        int cs = c ^ (row & 7);
        *reinterpret_cast<float4*>(&lB[row * K + cs * 8]) = v;
    }
    __syncthreads();

    const int row0 = blockIdx.x * 128 + w * 32;
    // clamped A row base offsets for the 2 m-fragments
    size_t aoff[2];
    #pragma unroll
    for (int mr = 0; mr < 2; ++mr) {
        int gr = row0 + mr * 16 + lr;
        if (gr >= M) gr = M - 1;
        aoff[mr] = (size_t)gr * K;
    }

    f32x4 acc[2][NT] = {};
    #pragma unroll
    for (int ks = 0; ks < NKS; ++ks) {
        const int kk = ks * 32 + lq * 8;         // element offset of this frag
        bf16x8 aF[2];
        #pragma unroll
        for (int mr = 0; mr < 2; ++mr) {
            if (AF32) {
                float4 v0 = *reinterpret_cast<const float4*>(&Af[aoff[mr] + kk]);
                float4 v1 = *reinterpret_cast<const float4*>(&Af[aoff[mr] + kk + 4]);
                bf16x8 a;
                a[0] = (short)f2b(v0.x); a[1] = (short)f2b(v0.y);
                a[2] = (short)f2b(v0.z); a[3] = (short)f2b(v0.w);
                a[4] = (short)f2b(v1.x); a[5] = (short)f2b(v1.y);
                a[6] = (short)f2b(v1.z); a[7] = (short)f2b(v1.w);
                aF[mr] = a;
            } else {
                aF[mr] = *reinterpret_cast<const bf16x8*>(&Ab[aoff[mr] + kk]);
            }
        }
        const int cbase = ks * 4 + lq;           // 16B chunk index of this k-window
        bf16x8 bF[NT];
        #pragma unroll
        for (int nr = 0; nr < NT; ++nr) {
            int row = nr * 16 + lr;
            int cs = cbase ^ (lr & 7);
            bF[nr] = *reinterpret_cast<const bf16x8*>(&lB[row * K + cs * 8]);
        }
        #pragma unroll
        for (int mr = 0; mr < 2; ++mr)
            #pragma unroll
            for (int nr = 0; nr < NT; ++nr)
                acc[mr][nr] = __builtin_amdgcn_mfma_f32_16x16x32_bf16(aF[mr], bF[nr], acc[mr][nr], 0, 0, 0);
    }

    // ---- epilogue: C store + fused el/er (C/D layout: col=lr, row=lq*4+reg [m89]) ----
    float alv[NT], arv[NT];
    #pragma unroll
    for (int nr = 0; nr < NT; ++nr) {
        int c = nr * 16 + lr;
        alv[nr] = (c < OUTW) ? al[c] : 0.f;
        arv[nr] = (c < OUTW) ? ar[c] : 0.f;
    }
    #pragma unroll
    for (int mr = 0; mr < 2; ++mr) {
        #pragma unroll
        for (int reg = 0; reg < 4; ++reg) {
            int gr = row0 + mr * 16 + lq * 4 + reg;
            bool ok = gr < M;
            if (ok) {
                #pragma unroll
                for (int nr = 0; nr < NT; ++nr) {
                    int gc = nr * 16 + lr;
                    if (gc < OUTW) C[(size_t)gr * OUTW + gc] = f2b(acc[mr][nr][reg]);
                }
            }
            float pl[NH] = {}, pr[NH] = {};
            #pragma unroll
            for (int nr = 0; nr < NT; ++nr) {
                int hidx = (NH == 1) ? 0 : (nr >> 1);
                pl[hidx] = fmaf(acc[mr][nr][reg], alv[nr], pl[hidx]);
                pr[hidx] = fmaf(acc[mr][nr][reg], arv[nr], pr[hidx]);
            }
            #pragma unroll
            for (int o = 8; o >= 1; o >>= 1) {
                #pragma unroll
                for (int hh = 0; hh < NH; ++hh) {
                    pl[hh] += __shfl_xor(pl[hh], o);
                    pr[hh] += __shfl_xor(pr[hh], o);
                }
            }
            if (ok && lr == 0) {
                #pragma unroll
                for (int hh = 0; hh < NH; ++hh) {
                    el[gr * NH + hh] = pl[hh];
                    er[gr * NH + hh] = pr[hh];
                }
            }
        }
    }
}

// ============================== aggregation (fused, no-max softmax) ==============================
// Safe without max-subtraction: e = leaky_relu(el+er) ~ O(10) << 88, exp cannot overflow.

template<bool RELU>
__global__ __launch_bounds__(256) void agg4v4(const u32* __restrict__ h,   // [N][64] dwords
                                              const float4* __restrict__ el4,
                                              const float4* __restrict__ er4,
                                              const float* __restrict__ bias,
                                              const int* __restrict__ rowptr,
                                              const int* __restrict__ csrc,
                                              u32* __restrict__ out, int N) {
    __shared__ float4 s_ew[4][CAP];
    __shared__ int s_sid[4][CAP];
    const int wslot = threadIdx.x >> 6, lane = threadIdx.x & 63;
    const int wid = blockIdx.x * 4 + wslot;
    if (wid >= N) return;
    const int beg = rowptr[wid];
    const int deg = rowptr[wid + 1] - beg;
    const float4 er = er4[wid];
    const int hh = lane >> 4;
    const float2 bv = reinterpret_cast<const float2*>(bias)[lane];
    float accA = 0.f, accB = 0.f, invs;

    if (deg <= CAP) {
        float s0 = 0.f, s1 = 0.f, s2 = 0.f, s3 = 0.f;
        for (int base = 0; base < deg; base += 64) {
            int j = base + lane;
            if (j < deg) {
                int sid = csrc[beg + j];
                float4 ev = el4[sid];
                float e0 = ev.x + er.x; e0 = e0 > 0.f ? e0 : 0.2f * e0;
                float e1 = ev.y + er.y; e1 = e1 > 0.f ? e1 : 0.2f * e1;
                float e2 = ev.z + er.z; e2 = e2 > 0.f ? e2 : 0.2f * e2;
                float e3 = ev.w + er.w; e3 = e3 > 0.f ? e3 : 0.2f * e3;
                float p0 = __expf(e0), p1 = __expf(e1), p2 = __expf(e2), p3 = __expf(e3);
                s_sid[wslot][j] = sid;
                s_ew[wslot][j] = make_float4(p0, p1, p2, p3);
                s0 += p0; s1 += p1; s2 += p2; s3 += p3;
            }
        }
        #pragma unroll
        for (int o = 32; o >= 1; o >>= 1) {
            s0 += __shfl_xor(s0, o); s1 += __shfl_xor(s1, o);
            s2 += __shfl_xor(s2, o); s3 += __shfl_xor(s3, o);
        }
        float sh = hh == 0 ? s0 : hh == 1 ? s1 : hh == 2 ? s2 : s3;
        invs = (deg > 0) ? 1.f / sh : 0.f;
        const float* ewf = reinterpret_cast<const float*>(&s_ew[wslot][0]);
        const int* sidp = &s_sid[wslot][0];
        float a[8] = {}, b[8] = {};
        int p = 0;
        const int deg8 = deg & ~7;
        for (; p < deg8; p += 8) {
            int sid[8]; u32 hv[8]; float wg[8];
            #pragma unroll
            for (int k = 0; k < 8; ++k) sid[k] = sidp[p + k];
            #pragma unroll
            for (int k = 0; k < 8; ++k) hv[k] = h[(size_t)sid[k] * 64 + lane];
            #pragma unroll
            for (int k = 0; k < 8; ++k) wg[k] = ewf[(p + k) * 4 + hh];
            #pragma unroll
            for (int k = 0; k < 8; ++k) {
                a[k] = fmaf(wg[k], bflo(hv[k]), a[k]);
                b[k] = fmaf(wg[k], bfhi(hv[k]), b[k]);
            }
        }
        for (; p < deg; ++p) {
            int sid = sidp[p];
            float wg = ewf[p * 4 + hh];
            u32 hv = h[(size_t)sid * 64 + lane];
            a[0] = fmaf(wg, bflo(hv), a[0]);
            b[0] = fmaf(wg, bfhi(hv), b[0]);
        }
        accA = ((a[0] + a[1]) + (a[2] + a[3])) + ((a[4] + a[5]) + (a[6] + a[7]));
        accB = ((b[0] + b[1]) + (b[2] + b[3])) + ((b[4] + b[5]) + (b[6] + b[7]));
    } else {
        float er_h = hh == 0 ? er.x : hh == 1 ? er.y : hh == 2 ? er.z : er.w;
        float s = 0.f;
        for (int q = beg; q < beg + deg; ++q) {
            int sid = csrc[q];
            float4 ev = el4[sid];
            float e = (hh == 0 ? ev.x : hh == 1 ? ev.y : hh == 2 ? ev.z : ev.w) + er_h;
            e = e > 0.f ? e : 0.2f * e;
            float pe = __expf(e);
            u32 hv = h[(size_t)sid * 64 + lane];
            s += pe;
            accA = fmaf(pe, bflo(hv), accA);
            accB = fmaf(pe, bfhi(hv), accB);
        }
        invs = 1.f / s;
    }
    float oA = accA * invs + bv.x;
    float oB = accB * invs + bv.y;
    if (RELU) { oA = fmaxf(oA, 0.f); oB = fmaxf(oB, 0.f); }
    out[(size_t)wid * 64 + lane] = ((u32)f2b(oB) << 16) | (u32)f2b(oA);
}

// single head + bias + log_softmax(40); h [N,40] bf16, out fp32
__global__ __launch_bounds__(256) void agg1v4(const u16* __restrict__ h,
                                              const float* __restrict__ el,
                                              const float* __restrict__ er,
                                              const float* __restrict__ bias,
                                              const int* __restrict__ rowptr,
                                              const int* __restrict__ csrc,
                                              float* __restrict__ out, int N) {
    __shared__ float s_ew[4][CAP];
    __shared__ int s_sid[4][CAP];
    const int wslot = threadIdx.x >> 6, lane = threadIdx.x & 63;
    const int wid = blockIdx.x * 4 + wslot;
    if (wid >= N) return;
    const int beg = rowptr[wid];
    const int deg = rowptr[wid + 1] - beg;
    const float ern = er[wid];
    const int ll = lane < 40 ? lane : 39;
    float acc = 0.f, invs;

    if (deg <= CAP) {
        float s = 0.f;
        for (int base = 0; base < deg; base += 64) {
            int j = base + lane;
            if (j < deg) {
                int sid = csrc[beg + j];
                float e = el[sid] + ern; e = e > 0.f ? e : 0.2f * e;
                float pe = __expf(e);
                s_sid[wslot][j] = sid;
                s_ew[wslot][j] = pe;
                s += pe;
            }
        }
        #pragma unroll
        for (int o = 32; o >= 1; o >>= 1) s += __shfl_xor(s, o);
        invs = (deg > 0) ? 1.f / s : 0.f;
        float a[8] = {};
        int p = 0;
        const int deg8 = deg & ~7;
        for (; p < deg8; p += 8) {
            int sid[8]; float x[8], wg[8];
            #pragma unroll
            for (int k = 0; k < 8; ++k) sid[k] = s_sid[wslot][p + k];
            #pragma unroll
            for (int k = 0; k < 8; ++k) x[k] = b2f(h[(size_t)sid[k] * 40 + ll]);
            #pragma unroll
            for (int k = 0; k < 8; ++k) wg[k] = s_ew[wslot][p + k];
            #pragma unroll
            for (int k = 0; k < 8; ++k) a[k] = fmaf(wg[k], x[k], a[k]);
        }
        for (; p < deg; ++p)
            a[0] = fmaf(s_ew[wslot][p], b2f(h[(size_t)s_sid[wslot][p] * 40 + ll]), a[0]);
        acc = ((a[0] + a[1]) + (a[2] + a[3])) + ((a[4] + a[5]) + (a[6] + a[7]));
    } else {
        float s = 0.f;
        for (int q = beg; q < beg + deg; ++q) {
            int sid = csrc[q];
            float e = el[sid] + ern; e = e > 0.f ? e : 0.2f * e;
            float pe = __expf(e);
            s += pe;
            acc = fmaf(pe, b2f(h[(size_t)sid * 40 + ll]), acc);
        }
        invs = 1.f / s;
    }
    float v = acc * invs + ((lane < 40) ? bias[lane] : 0.f);
    float vv = (lane < 40) ? v : -INFINITY;
    float mx = vv;
    #pragma unroll
    for (int o = 32; o >= 1; o >>= 1) mx = fmaxf(mx, __shfl_xor(mx, o));
    float ex = (lane < 40) ? __expf(v - mx) : 0.f;
    float se = ex;
    #pragma unroll
    for (int o = 32; o >= 1; o >>= 1) se += __shfl_xor(se, o);
    if (lane < 40) out[(size_t)wid * 40 + lane] = v - mx - logf(se);
}

// ============================== launch ==============================

extern "C" void kernel_launch(void* const* d_in, const int* in_sizes, int n_in,
                              void* d_out, int out_size, void* d_ws, size_t ws_size,
                              hipStream_t stream) {
    const float* feat = (const float*)d_in[0];
    const float* W1  = (const float*)d_in[1];
    const float* al1 = (const float*)d_in[2];
    const float* ar1 = (const float*)d_in[3];
    const float* b1  = (const float*)d_in[4];
    const float* W2  = (const float*)d_in[5];
    const float* al2 = (const float*)d_in[6];
    const float* ar2 = (const float*)d_in[7];
    const float* b2  = (const float*)d_in[8];
    const float* W3  = (const float*)d_in[9];
    const float* al3 = (const float*)d_in[10];
    const float* ar3 = (const float*)d_in[11];
    const float* b3  = (const float*)d_in[12];
    const int*   src = (const int*)d_in[13];
    const int*   dst = (const int*)d_in[14];
    float* out = (float*)d_out;
    const int N = NN, E = NE;

    char* ws = (char*)d_ws;
    size_t off = 0;
    auto alloc = [&](size_t bytes) -> char* {
        char* p = ws + off;
        off += (bytes + 255) & ~(size_t)255;
        return p;
    };
    int* deg    = (int*)alloc((size_t)N * 4);
    int* rowptr = (int*)alloc((size_t)(N + 1) * 4);
    int* bsum   = (int*)alloc(512 * 4);
    int* gcur   = (int*)alloc(256 * 4);
    int* csrc   = (int*)alloc((size_t)E * 4);
    long long* ebuf = (long long*)alloc((size_t)E * 8);
    float* el   = (float*)alloc((size_t)N * 4 * 4);
    float* er   = (float*)alloc((size_t)N * 4 * 4);
    u16* hb     = (u16*)alloc((size_t)N * 128 * 2);
    u16* xb     = (u16*)alloc((size_t)N * 128 * 2);
    u16* h3     = (u16*)alloc((size_t)N * 40 * 2 + 256);
    u16* W1t    = (u16*)alloc((size_t)128 * 256 * 2);
    u16* W2t    = (u16*)alloc((size_t)128 * 128 * 2);
    u16* W3t    = (u16*)alloc((size_t)48 * 128 * 2);

    // ---- CSR rowptr ----
    hipMemsetAsync(deg, 0, (size_t)N * 4, stream);
    hist_kernel<<<(E + 255) / 256, 256, 0, stream>>>(dst, deg, E);
    int NB = (N + 255) / 256;
    scan_local<<<NB, 256, 0, stream>>>(deg, rowptr, bsum, N);
    scan_bsum<<<1, 512, 0, stream>>>(bsum, NB);
    scan_add<<<(N + 255) / 256, 256, 0, stream>>>(rowptr, bsum, N);
    // ---- bucketed edge partition -> csrc ----
    initcur<<<1, 256, 0, stream>>>(rowptr, gcur);
    part1<<<256, 256, 0, stream>>>(src, dst, gcur, ebuf);
    part2<<<NBUC, 256, 0, stream>>>(rowptr, ebuf, csrc);

    // ---- weight prep ----
    transW<<<(128 * 256 + 255) / 256, 256, 0, stream>>>(W1, W1t, 256, 128, 128);
    transW<<<(128 * 128 + 255) / 256, 256, 0, stream>>>(W2, W2t, 128, 128, 128);
    transW<<<(48 * 128 + 255) / 256, 256, 0, stream>>>(W3, W3t, 128, 40, 48);

    int gemmGrid = (N + 127) / 128;
    int nodeGrid = (N + 3) / 4;

    // ---- layer 1 (fp32 A, cast fused into fragment load) ----
    gemm_breg<256, 8, 128, true, 4><<<gemmGrid, 256, 0, stream>>>(feat, W1t, al1, ar1, hb, el, er, N);
    agg4v4<true><<<nodeGrid, 256, 0, stream>>>((const u32*)hb, (const float4*)el, (const float4*)er,
                                               b1, rowptr, csrc, (u32*)xb, N);

    // ---- layer 2 ----
    gemm_breg<128, 8, 128, false, 4><<<gemmGrid, 256, 0, stream>>>(xb, W2t, al2, ar2, hb, el, er, N);
    agg4v4<true><<<nodeGrid, 256, 0, stream>>>((const u32*)hb, (const float4*)el, (const float4*)er,
                                               b2, rowptr, csrc, (u32*)xb, N);

    // ---- layer 3 (+ fused log_softmax) ----
    gemm_breg<128, 3, 40, false, 1><<<gemmGrid, 256, 0, stream>>>(xb, W3t, al3, ar3, h3, el, er, N);
    agg1v4<<<nodeGrid, 256, 0, stream>>>(h3, el, er, b3, rowptr, csrc, out, N);
}

// Round 8
// 342.543 us; speedup vs baseline: 1.3426x; 1.0471x over previous
//
#include <hip/hip_runtime.h>
#include <hip/hip_bf16.h>
#include <math.h>

#define NN 100000
#define NE 1000000
#define CAP 128
#define NPB 512                          // nodes per bucket (pow2, shift 9)
#define NBUC ((NN + NPB - 1) / NPB)      // 196
#define CAPB 8192                        // max staged edges per bucket
#define P1B 512                          // part1 blocks
#define P1E ((NE + P1B - 1) / P1B)       // 1954 edges per part1 block

typedef __attribute__((ext_vector_type(8))) short bf16x8;
typedef __attribute__((ext_vector_type(4))) float f32x4;
typedef unsigned int u32;
typedef unsigned short u16;
typedef unsigned long long u64;

__device__ __forceinline__ u16 f2b(float f) {
    __hip_bfloat16 h = __float2bfloat16(f);
    return *reinterpret_cast<u16*>(&h);
}
__device__ __forceinline__ float b2f(u16 u) {
    __hip_bfloat16 h = *reinterpret_cast<__hip_bfloat16*>(&u);
    return __bfloat162float(h);
}
__device__ __forceinline__ float bflo(u32 v) { return __uint_as_float(v << 16); }
__device__ __forceinline__ float bfhi(u32 v) { return __uint_as_float(v & 0xffff0000u); }

// ============================== CSR: degree + rowptr ==============================

__global__ void hist_kernel(const int* __restrict__ dst, int* __restrict__ deg, int E) {
    int i = blockIdx.x * blockDim.x + threadIdx.x;
    if (i < E) atomicAdd(&deg[dst[i]], 1);
}

__global__ void scan_local(const int* __restrict__ deg, int* __restrict__ rowptr,
                           int* __restrict__ bsum, int N) {
    __shared__ int s[256];
    int i = blockIdx.x * 256 + threadIdx.x;
    int v = (i < N) ? deg[i] : 0;
    s[threadIdx.x] = v;
    __syncthreads();
    #pragma unroll
    for (int off = 1; off < 256; off <<= 1) {
        int t = (threadIdx.x >= off) ? s[threadIdx.x - off] : 0;
        __syncthreads();
        s[threadIdx.x] += t;
        __syncthreads();
    }
    if (i < N) rowptr[i + 1] = s[threadIdx.x];
    if (threadIdx.x == 255) bsum[blockIdx.x] = s[255];
}

__global__ void scan_bsum(int* __restrict__ bsum, int NB) {
    __shared__ int s[512];
    int v = (threadIdx.x < NB) ? bsum[threadIdx.x] : 0;
    s[threadIdx.x] = v;
    __syncthreads();
    for (int off = 1; off < 512; off <<= 1) {
        int t = (threadIdx.x >= off) ? s[threadIdx.x - off] : 0;
        __syncthreads();
        s[threadIdx.x] += t;
        __syncthreads();
    }
    if (threadIdx.x < NB) bsum[threadIdx.x] = s[threadIdx.x] - v;  // exclusive
}

__global__ void scan_add(int* __restrict__ rowptr, const int* __restrict__ bsum, int N) {
    int i = blockIdx.x * blockDim.x + threadIdx.x;
    if (i < N) rowptr[i + 1] += bsum[i >> 8];
    if (i == 0) rowptr[0] = 0;
}

// ============================== CSR: bucketed edge partition ==============================

__global__ void initcur(const int* __restrict__ rowptr, int* __restrict__ gcur) {
    int b = threadIdx.x;
    if (b < NBUC) gcur[b] = rowptr[b << 9];
}

__global__ __launch_bounds__(256) void part1(const int* __restrict__ src,
                                             const int* __restrict__ dst,
                                             int* __restrict__ gcur,
                                             long long* __restrict__ ebuf) {
    __shared__ int cnt[256], sex[256], base[256], cur2[256], scn[256];
    __shared__ long long stage[P1E];
    const int tid = threadIdx.x;
    const int e0 = blockIdx.x * P1E;
    const int e1 = min(e0 + P1E, NE);
    cnt[tid] = 0;
    __syncthreads();
    for (int i = e0 + tid; i < e1; i += 256)
        atomicAdd(&cnt[dst[i] >> 9], 1);
    __syncthreads();
    int v = cnt[tid];
    scn[tid] = v;
    __syncthreads();
    #pragma unroll
    for (int off = 1; off < 256; off <<= 1) {
        int t = (tid >= off) ? scn[tid - off] : 0;
        __syncthreads();
        scn[tid] += t;
        __syncthreads();
    }
    sex[tid] = scn[tid] - v;  // exclusive scan
    if (tid < NBUC) base[tid] = (v > 0) ? atomicAdd(&gcur[tid], v) : 0;
    cur2[tid] = 0;
    __syncthreads();
    for (int i = e0 + tid; i < e1; i += 256) {
        int d = dst[i], s = src[i];
        int b = d >> 9;
        int slot = sex[b] + atomicAdd(&cur2[b], 1);
        stage[slot] = ((long long)(u32)d << 32) | (u32)s;
    }
    __syncthreads();
    const int tot = e1 - e0;
    for (int i = tid; i < tot; i += 256) {
        long long ll = stage[i];
        int b = (int)((u64)ll >> 32) >> 9;
        ebuf[(size_t)base[b] + (i - sex[b])] = ll;
    }
}

__global__ __launch_bounds__(256) void part2(const int* __restrict__ rowptr,
                                             const long long* __restrict__ ebuf,
                                             int* __restrict__ csrc) {
    __shared__ int nb[NPB], cnt[NPB];
    __shared__ int stage[CAPB];
    const int tid = threadIdx.x;
    const int n0 = blockIdx.x << 9;
    const int nn = min(NPB, NN - n0);
    const int estart = rowptr[n0];
    const int eend = rowptr[n0 + nn];
    const int tot = eend - estart;
    for (int i = tid; i < nn; i += 256) {
        nb[i] = rowptr[n0 + i] - estart;
        cnt[i] = 0;
    }
    __syncthreads();
    if (tot <= CAPB) {
        for (int i = estart + tid; i < eend; i += 256) {
            long long ll = ebuf[i];
            int ln = (int)((u64)ll >> 32) - n0;
            int pos = nb[ln] + atomicAdd(&cnt[ln], 1);
            stage[pos] = (int)ll;
        }
        __syncthreads();
        for (int i = tid; i < tot; i += 256) csrc[estart + i] = stage[i];
    } else {
        for (int i = estart + tid; i < eend; i += 256) {
            long long ll = ebuf[i];
            int ln = (int)((u64)ll >> 32) - n0;
            int pos = nb[ln] + atomicAdd(&cnt[ln], 1);
            csrc[estart + pos] = (int)ll;
        }
    }
}

// ============================== weight prep (fused 3 layers) ==============================

__global__ void transW3(const float* __restrict__ W1, u16* __restrict__ W1t,
                        const float* __restrict__ W2, u16* __restrict__ W2t,
                        const float* __restrict__ W3, u16* __restrict__ W3t) {
    int idx = blockIdx.x * 256 + threadIdx.x;
    if (idx < 32768) {                    // W1: K=256, Nin=128, pad 128
        int n = idx / 256, k = idx % 256;
        W1t[idx] = f2b(W1[(size_t)k * 128 + n]);
    } else if (idx < 32768 + 16384) {     // W2: K=128, Nin=128
        int j = idx - 32768;
        int n = j / 128, k = j % 128;
        W2t[j] = f2b(W2[(size_t)k * 128 + n]);
    } else if (idx < 32768 + 16384 + 6144) {  // W3: K=128, Nin=40, pad 48
        int j = idx - 32768 - 16384;
        int n = j / 128, k = j % 128;
        W3t[j] = f2b((n < 40) ? W3[(size_t)k * 40 + n] : 0.f);
    }
}

// ============================== MFMA GEMM: B-in-LDS, A direct-to-reg ==============================
template<int K, int NT, int OUTW, bool AF32, int NH>
__global__ __launch_bounds__(256) void gemm_breg(const void* __restrict__ Ap_,
                                                 const u16* __restrict__ Wt,
                                                 const float* __restrict__ al,
                                                 const float* __restrict__ ar,
                                                 u16* __restrict__ C,
                                                 float* __restrict__ el,
                                                 float* __restrict__ er, int M) {
    constexpr int NB = NT * 16;
    constexpr int NKS = K / 32;          // MFMA k-steps
    constexpr int CHK = K / 8;           // 16B chunks per B row
    __shared__ u16 lB[NB * K];           // chunk c of row stored at c^(row&7)
    const int tid = threadIdx.x;
    const int w = tid >> 6, l = tid & 63;
    const int lr = l & 15, lq = l >> 4;
    const u16* Ab = (const u16*)Ap_;
    const float* Af = (const float*)Ap_;

    for (int idx = tid; idx < NB * CHK; idx += 256) {
        int row = idx / CHK, c = idx % CHK;
        float4 v = *reinterpret_cast<const float4*>(&Wt[(size_t)row * K + c * 8]);
        int cs = c ^ (row & 7);
        *reinterpret_cast<float4*>(&lB[row * K + cs * 8]) = v;
    }
    __syncthreads();

    const int row0 = blockIdx.x * 128 + w * 32;
    size_t aoff[2];
    #pragma unroll
    for (int mr = 0; mr < 2; ++mr) {
        int gr = row0 + mr * 16 + lr;
        if (gr >= M) gr = M - 1;
        aoff[mr] = (size_t)gr * K;
    }

    f32x4 acc[2][NT] = {};
    #pragma unroll
    for (int ks = 0; ks < NKS; ++ks) {
        const int kk = ks * 32 + lq * 8;
        bf16x8 aF[2];
        #pragma unroll
        for (int mr = 0; mr < 2; ++mr) {
            if (AF32) {
                float4 v0 = *reinterpret_cast<const float4*>(&Af[aoff[mr] + kk]);
                float4 v1 = *reinterpret_cast<const float4*>(&Af[aoff[mr] + kk + 4]);
                bf16x8 a;
                a[0] = (short)f2b(v0.x); a[1] = (short)f2b(v0.y);
                a[2] = (short)f2b(v0.z); a[3] = (short)f2b(v0.w);
                a[4] = (short)f2b(v1.x); a[5] = (short)f2b(v1.y);
                a[6] = (short)f2b(v1.z); a[7] = (short)f2b(v1.w);
                aF[mr] = a;
            } else {
                aF[mr] = *reinterpret_cast<const bf16x8*>(&Ab[aoff[mr] + kk]);
            }
        }
        const int cbase = ks * 4 + lq;
        bf16x8 bF[NT];
        #pragma unroll
        for (int nr = 0; nr < NT; ++nr) {
            int row = nr * 16 + lr;
            int cs = cbase ^ (lr & 7);
            bF[nr] = *reinterpret_cast<const bf16x8*>(&lB[row * K + cs * 8]);
        }
        #pragma unroll
        for (int mr = 0; mr < 2; ++mr)
            #pragma unroll
            for (int nr = 0; nr < NT; ++nr)
                acc[mr][nr] = __builtin_amdgcn_mfma_f32_16x16x32_bf16(aF[mr], bF[nr], acc[mr][nr], 0, 0, 0);
    }

    // epilogue: C store + fused el/er (C/D layout: col=lr, row=lq*4+reg [m89])
    float alv[NT], arv[NT];
    #pragma unroll
    for (int nr = 0; nr < NT; ++nr) {
        int c = nr * 16 + lr;
        alv[nr] = (c < OUTW) ? al[c] : 0.f;
        arv[nr] = (c < OUTW) ? ar[c] : 0.f;
    }
    #pragma unroll
    for (int mr = 0; mr < 2; ++mr) {
        #pragma unroll
        for (int reg = 0; reg < 4; ++reg) {
            int gr = row0 + mr * 16 + lq * 4 + reg;
            bool ok = gr < M;
            if (ok) {
                #pragma unroll
                for (int nr = 0; nr < NT; ++nr) {
                    int gc = nr * 16 + lr;
                    if (gc < OUTW) C[(size_t)gr * OUTW + gc] = f2b(acc[mr][nr][reg]);
                }
            }
            float pl[NH] = {}, pr[NH] = {};
            #pragma unroll
            for (int nr = 0; nr < NT; ++nr) {
                int hidx = (NH == 1) ? 0 : (nr >> 1);
                pl[hidx] = fmaf(acc[mr][nr][reg], alv[nr], pl[hidx]);
                pr[hidx] = fmaf(acc[mr][nr][reg], arv[nr], pr[hidx]);
            }
            #pragma unroll
            for (int o = 8; o >= 1; o >>= 1) {
                #pragma unroll
                for (int hh = 0; hh < NH; ++hh) {
                    pl[hh] += __shfl_xor(pl[hh], o);
                    pr[hh] += __shfl_xor(pr[hh], o);
                }
            }
            if (ok && lr == 0) {
                #pragma unroll
                for (int hh = 0; hh < NH; ++hh) {
                    el[gr * NH + hh] = pl[hh];
                    er[gr * NH + hh] = pr[hh];
                }
            }
        }
    }
}

// ============================== aggregation v5 ==============================
// Phase 1: lane j handles edge j: exp(leaky(el+er)) for 4 heads; store {w_h, sid<<8} pairs.
// Phase 2: per edge ONE ds_read_b64 (imm offset) + 1 v_or + saddr gather + 2 fma;
//          softmax sum accumulated inline (no butterfly).

template<bool RELU>
__global__ __launch_bounds__(256) void agg4v5(const char* __restrict__ hbase,  // h [N][64] dwords
                                              const float4* __restrict__ el4,
                                              const float4* __restrict__ er4,
                                              const float* __restrict__ bias,
                                              const int* __restrict__ rowptr,
                                              const int* __restrict__ csrc,
                                              u32* __restrict__ out, int N) {
    __shared__ u32 s_ed[4][CAP][8];      // [w0,so, w1,so, w2,so, w3,so]
    const int wslot = threadIdx.x >> 6, lane = threadIdx.x & 63;
    const int wid = blockIdx.x * 4 + wslot;
    if (wid >= N) return;
    const int beg = rowptr[wid];
    const int deg = rowptr[wid + 1] - beg;
    const float4 er = er4[wid];
    const int hh = lane >> 4;
    const u32 lshl = (u32)(lane << 2);
    const float2 bv = reinterpret_cast<const float2*>(bias)[lane];
    float accA, accB, invs;

    if (deg <= CAP) {
        for (int basej = 0; basej < deg; basej += 64) {
            int j = basej + lane;
            if (j < deg) {
                int sid = csrc[beg + j];
                float4 ev = el4[sid];
                float e0 = ev.x + er.x; e0 = e0 > 0.f ? e0 : 0.2f * e0;
                float e1 = ev.y + er.y; e1 = e1 > 0.f ? e1 : 0.2f * e1;
                float e2 = ev.z + er.z; e2 = e2 > 0.f ? e2 : 0.2f * e2;
                float e3 = ev.w + er.w; e3 = e3 > 0.f ? e3 : 0.2f * e3;
                u32 so = (u32)sid << 8;
                int2 v0 = make_int2(__float_as_int(__expf(e0)), (int)so);
                int2 v1 = make_int2(__float_as_int(__expf(e1)), (int)so);
                int2 v2 = make_int2(__float_as_int(__expf(e2)), (int)so);
                int2 v3 = make_int2(__float_as_int(__expf(e3)), (int)so);
                *reinterpret_cast<int2*>(&s_ed[wslot][j][0]) = v0;
                *reinterpret_cast<int2*>(&s_ed[wslot][j][2]) = v1;
                *reinterpret_cast<int2*>(&s_ed[wslot][j][4]) = v2;
                *reinterpret_cast<int2*>(&s_ed[wslot][j][6]) = v3;
            }
        }
        const u32* ebase = &s_ed[wslot][0][hh * 2];
        float a[8] = {}, b[8] = {}, sw[8] = {};
        int p = 0;
        const int deg8 = deg & ~7;
        for (; p < deg8; p += 8) {
            #pragma unroll
            for (int k = 0; k < 8; ++k) {
                int2 rv = *reinterpret_cast<const int2*>(ebase + (p + k) * 8);
                float wg = __int_as_float(rv.x);
                u32 hv = *reinterpret_cast<const u32*>(hbase + ((u32)rv.y | lshl));
                a[k] = fmaf(wg, bflo(hv), a[k]);
                b[k] = fmaf(wg, bfhi(hv), b[k]);
                sw[k] += wg;
            }
        }
        for (; p < deg; ++p) {
            int2 rv = *reinterpret_cast<const int2*>(ebase + p * 8);
            float wg = __int_as_float(rv.x);
            u32 hv = *reinterpret_cast<const u32*>(hbase + ((u32)rv.y | lshl));
            a[0] = fmaf(wg, bflo(hv), a[0]);
            b[0] = fmaf(wg, bfhi(hv), b[0]);
            sw[0] += wg;
        }
        accA = ((a[0] + a[1]) + (a[2] + a[3])) + ((a[4] + a[5]) + (a[6] + a[7]));
        accB = ((b[0] + b[1]) + (b[2] + b[3])) + ((b[4] + b[5]) + (b[6] + b[7]));
        float s = ((sw[0] + sw[1]) + (sw[2] + sw[3])) + ((sw[4] + sw[5]) + (sw[6] + sw[7]));
        invs = (deg > 0) ? 1.f / s : 0.f;
    } else {
        float er_h = hh == 0 ? er.x : hh == 1 ? er.y : hh == 2 ? er.z : er.w;
        float s = 0.f;
        accA = 0.f; accB = 0.f;
        for (int q = beg; q < beg + deg; ++q) {
            int sid = csrc[q];
            float4 ev = el4[sid];
            float e = (hh == 0 ? ev.x : hh == 1 ? ev.y : hh == 2 ? ev.z : ev.w) + er_h;
            e = e > 0.f ? e : 0.2f * e;
            float pe = __expf(e);
            u32 hv = *reinterpret_cast<const u32*>(hbase + (((u32)sid << 8) | lshl));
            s += pe;
            accA = fmaf(pe, bflo(hv), accA);
            accB = fmaf(pe, bfhi(hv), accB);
        }
        invs = 1.f / s;
    }
    float oA = accA * invs + bv.x;
    float oB = accB * invs + bv.y;
    if (RELU) { oA = fmaxf(oA, 0.f); oB = fmaxf(oB, 0.f); }
    out[(size_t)wid * 64 + lane] = ((u32)f2b(oB) << 16) | (u32)f2b(oA);
}

// single head + bias + log_softmax(40); h3 [N,40] bf16
__global__ __launch_bounds__(256) void agg1v5(const char* __restrict__ hbase,
                                              const float* __restrict__ el,
                                              const float* __restrict__ er,
                                              const float* __restrict__ bias,
                                              const int* __restrict__ rowptr,
                                              const int* __restrict__ csrc,
                                              float* __restrict__ out, int N) {
    __shared__ u32 s_ed[4][CAP][2];      // {w, sid*80}
    const int wslot = threadIdx.x >> 6, lane = threadIdx.x & 63;
    const int wid = blockIdx.x * 4 + wslot;
    if (wid >= N) return;
    const int beg = rowptr[wid];
    const int deg = rowptr[wid + 1] - beg;
    const float ern = er[wid];
    const int ll = lane < 40 ? lane : 39;
    const u32 lloff = (u32)(ll << 1);
    float acc, invs;

    if (deg <= CAP) {
        for (int basej = 0; basej < deg; basej += 64) {
            int j = basej + lane;
            if (j < deg) {
                int sid = csrc[beg + j];
                float e = el[sid] + ern; e = e > 0.f ? e : 0.2f * e;
                u32 so = (u32)sid * 80u;
                *reinterpret_cast<int2*>(&s_ed[wslot][j][0]) =
                    make_int2(__float_as_int(__expf(e)), (int)so);
            }
        }
        const u32* ebase = &s_ed[wslot][0][0];
        float a[8] = {}, sw[8] = {};
        int p = 0;
        const int deg8 = deg & ~7;
        for (; p < deg8; p += 8) {
            #pragma unroll
            for (int k = 0; k < 8; ++k) {
                int2 rv = *reinterpret_cast<const int2*>(ebase + (p + k) * 2);
                float wg = __int_as_float(rv.x);
                u16 hv = *reinterpret_cast<const u16*>(hbase + ((u32)rv.y + lloff));
                a[k] = fmaf(wg, b2f(hv), a[k]);
                sw[k] += wg;
            }
        }
        for (; p < deg; ++p) {
            int2 rv = *reinterpret_cast<const int2*>(ebase + p * 2);
            float wg = __int_as_float(rv.x);
            u16 hv = *reinterpret_cast<const u16*>(hbase + ((u32)rv.y + lloff));
            a[0] = fmaf(wg, b2f(hv), a[0]);
            sw[0] += wg;
        }
        acc = ((a[0] + a[1]) + (a[2] + a[3])) + ((a[4] + a[5]) + (a[6] + a[7]));
        float s = ((sw[0] + sw[1]) + (sw[2] + sw[3])) + ((sw[4] + sw[5]) + (sw[6] + sw[7]));
        invs = (deg > 0) ? 1.f / s : 0.f;
    } else {
        float s = 0.f;
        acc = 0.f;
        for (int q = beg; q < beg + deg; ++q) {
            int sid = csrc[q];
            float e = el[sid] + ern; e = e > 0.f ? e : 0.2f * e;
            float pe = __expf(e);
            u16 hv = *reinterpret_cast<const u16*>(hbase + ((u32)sid * 80u + lloff));
            s += pe;
            acc = fmaf(pe, b2f(hv), acc);
        }
        invs = 1.f / s;
    }
    float v = acc * invs + ((lane < 40) ? bias[lane] : 0.f);
    float vv = (lane < 40) ? v : -INFINITY;
    float mx = vv;
    #pragma unroll
    for (int o = 32; o >= 1; o >>= 1) mx = fmaxf(mx, __shfl_xor(mx, o));
    float ex = (lane < 40) ? __expf(v - mx) : 0.f;
    float se = ex;
    #pragma unroll
    for (int o = 32; o >= 1; o >>= 1) se += __shfl_xor(se, o);
    if (lane < 40) out[(size_t)wid * 40 + lane] = v - mx - logf(se);
}

// ============================== launch ==============================

extern "C" void kernel_launch(void* const* d_in, const int* in_sizes, int n_in,
                              void* d_out, int out_size, void* d_ws, size_t ws_size,
                              hipStream_t stream) {
    const float* feat = (const float*)d_in[0];
    const float* W1  = (const float*)d_in[1];
    const float* al1 = (const float*)d_in[2];
    const float* ar1 = (const float*)d_in[3];
    const float* b1  = (const float*)d_in[4];
    const float* W2  = (const float*)d_in[5];
    const float* al2 = (const float*)d_in[6];
    const float* ar2 = (const float*)d_in[7];
    const float* b2  = (const float*)d_in[8];
    const float* W3  = (const float*)d_in[9];
    const float* al3 = (const float*)d_in[10];
    const float* ar3 = (const float*)d_in[11];
    const float* b3  = (const float*)d_in[12];
    const int*   src = (const int*)d_in[13];
    const int*   dst = (const int*)d_in[14];
    float* out = (float*)d_out;
    const int N = NN, E = NE;

    char* ws = (char*)d_ws;
    size_t off = 0;
    auto alloc = [&](size_t bytes) -> char* {
        char* p = ws + off;
        off += (bytes + 255) & ~(size_t)255;
        return p;
    };
    int* deg    = (int*)alloc((size_t)N * 4);
    int* rowptr = (int*)alloc((size_t)(N + 1) * 4);
    int* bsum   = (int*)alloc(512 * 4);
    int* gcur   = (int*)alloc(256 * 4);
    int* csrc   = (int*)alloc((size_t)E * 4);
    long long* ebuf = (long long*)alloc((size_t)E * 8);
    float* el   = (float*)alloc((size_t)N * 4 * 4);
    float* er   = (float*)alloc((size_t)N * 4 * 4);
    u16* hb     = (u16*)alloc((size_t)N * 128 * 2);
    u16* xb     = (u16*)alloc((size_t)N * 128 * 2);
    u16* h3     = (u16*)alloc((size_t)N * 40 * 2 + 256);
    u16* W1t    = (u16*)alloc((size_t)128 * 256 * 2);
    u16* W2t    = (u16*)alloc((size_t)128 * 128 * 2);
    u16* W3t    = (u16*)alloc((size_t)48 * 128 * 2);

    // ---- CSR rowptr ----
    hipMemsetAsync(deg, 0, (size_t)N * 4, stream);
    hist_kernel<<<(E + 255) / 256, 256, 0, stream>>>(dst, deg, E);
    int NB = (N + 255) / 256;
    scan_local<<<NB, 256, 0, stream>>>(deg, rowptr, bsum, N);
    scan_bsum<<<1, 512, 0, stream>>>(bsum, NB);
    scan_add<<<(N + 255) / 256, 256, 0, stream>>>(rowptr, bsum, N);
    // ---- bucketed edge partition -> csrc ----
    initcur<<<1, 256, 0, stream>>>(rowptr, gcur);
    part1<<<P1B, 256, 0, stream>>>(src, dst, gcur, ebuf);
    part2<<<NBUC, 256, 0, stream>>>(rowptr, ebuf, csrc);

    // ---- weight prep (one kernel) ----
    transW3<<<(32768 + 16384 + 6144 + 255) / 256, 256, 0, stream>>>(W1, W1t, W2, W2t, W3, W3t);

    int gemmGrid = (N + 127) / 128;
    int nodeGrid = (N + 3) / 4;

    // ---- layer 1 ----
    gemm_breg<256, 8, 128, true, 4><<<gemmGrid, 256, 0, stream>>>(feat, W1t, al1, ar1, hb, el, er, N);
    agg4v5<true><<<nodeGrid, 256, 0, stream>>>((const char*)hb, (const float4*)el, (const float4*)er,
                                               b1, rowptr, csrc, (u32*)xb, N);

    // ---- layer 2 ----
    gemm_breg<128, 8, 128, false, 4><<<gemmGrid, 256, 0, stream>>>(xb, W2t, al2, ar2, hb, el, er, N);
    agg4v5<true><<<nodeGrid, 256, 0, stream>>>((const char*)hb, (const float4*)el, (const float4*)er,
                                               b2, rowptr, csrc, (u32*)xb, N);

    // ---- layer 3 (+ fused log_softmax) ----
    gemm_breg<128, 3, 40, false, 1><<<gemmGrid, 256, 0, stream>>>(xb, W3t, al3, ar3, h3, el, er, N);
    agg1v5<<<nodeGrid, 256, 0, stream>>>((const char*)h3, el, er, b3, rowptr, csrc, out, N);
}

// Round 9
// 338.485 us; speedup vs baseline: 1.3587x; 1.0120x over previous
//
#include <hip/hip_runtime.h>
#include <hip/hip_bf16.h>
#include <math.h>

#define NN 100000
#define NE 1000000
#define CAP 128
#define NPB 512                          // nodes per bucket (pow2, shift 9)
#define NBUC ((NN + NPB - 1) / NPB)      // 196
#define CAPB 8192                        // max staged edges per bucket
#define P1B 512                          // part1 blocks
#define P1E ((NE + P1B - 1) / P1B)       // 1954 edges per part1 block

typedef __attribute__((ext_vector_type(8))) short bf16x8;
typedef __attribute__((ext_vector_type(4))) float f32x4;
typedef unsigned int u32;
typedef unsigned short u16;
typedef unsigned long long u64;

__device__ __forceinline__ u16 f2b(float f) {
    __hip_bfloat16 h = __float2bfloat16(f);
    return *reinterpret_cast<u16*>(&h);
}
__device__ __forceinline__ float b2f(u16 u) {
    __hip_bfloat16 h = *reinterpret_cast<__hip_bfloat16*>(&u);
    return __bfloat162float(h);
}
__device__ __forceinline__ float bflo(u32 v) { return __uint_as_float(v << 16); }
__device__ __forceinline__ float bfhi(u32 v) { return __uint_as_float(v & 0xffff0000u); }

// ============================== CSR: degree + rowptr ==============================

__global__ void hist_kernel(const int* __restrict__ dst, int* __restrict__ deg, int E) {
    int i = blockIdx.x * blockDim.x + threadIdx.x;
    if (i < E) atomicAdd(&deg[dst[i]], 1);
}

__global__ void scan_local(const int* __restrict__ deg, int* __restrict__ rowptr,
                           int* __restrict__ bsum, int N) {
    __shared__ int s[256];
    int i = blockIdx.x * 256 + threadIdx.x;
    int v = (i < N) ? deg[i] : 0;
    s[threadIdx.x] = v;
    __syncthreads();
    #pragma unroll
    for (int off = 1; off < 256; off <<= 1) {
        int t = (threadIdx.x >= off) ? s[threadIdx.x - off] : 0;
        __syncthreads();
        s[threadIdx.x] += t;
        __syncthreads();
    }
    if (i < N) rowptr[i + 1] = s[threadIdx.x];
    if (threadIdx.x == 255) bsum[blockIdx.x] = s[255];
}

__global__ void scan_bsum(int* __restrict__ bsum, int NB) {
    __shared__ int s[512];
    int v = (threadIdx.x < NB) ? bsum[threadIdx.x] : 0;
    s[threadIdx.x] = v;
    __syncthreads();
    for (int off = 1; off < 512; off <<= 1) {
        int t = (threadIdx.x >= off) ? s[threadIdx.x - off] : 0;
        __syncthreads();
        s[threadIdx.x] += t;
        __syncthreads();
    }
    if (threadIdx.x < NB) bsum[threadIdx.x] = s[threadIdx.x] - v;  // exclusive
}

__global__ void scan_add(int* __restrict__ rowptr, const int* __restrict__ bsum, int N) {
    int i = blockIdx.x * blockDim.x + threadIdx.x;
    if (i < N) rowptr[i + 1] += bsum[i >> 8];
    if (i == 0) rowptr[0] = 0;
}

// ============================== CSR: bucketed edge partition ==============================

__global__ void initcur(const int* __restrict__ rowptr, int* __restrict__ gcur) {
    int b = threadIdx.x;
    if (b < NBUC) gcur[b] = rowptr[b << 9];
}

__global__ __launch_bounds__(256) void part1(const int* __restrict__ src,
                                             const int* __restrict__ dst,
                                             int* __restrict__ gcur,
                                             long long* __restrict__ ebuf) {
    __shared__ int cnt[256], sex[256], base[256], cur2[256], scn[256];
    __shared__ long long stage[P1E];
    const int tid = threadIdx.x;
    const int e0 = blockIdx.x * P1E;
    const int e1 = min(e0 + P1E, NE);
    cnt[tid] = 0;
    __syncthreads();
    for (int i = e0 + tid; i < e1; i += 256)
        atomicAdd(&cnt[dst[i] >> 9], 1);
    __syncthreads();
    int v = cnt[tid];
    scn[tid] = v;
    __syncthreads();
    #pragma unroll
    for (int off = 1; off < 256; off <<= 1) {
        int t = (tid >= off) ? scn[tid - off] : 0;
        __syncthreads();
        scn[tid] += t;
        __syncthreads();
    }
    sex[tid] = scn[tid] - v;  // exclusive scan
    if (tid < NBUC) base[tid] = (v > 0) ? atomicAdd(&gcur[tid], v) : 0;
    cur2[tid] = 0;
    __syncthreads();
    for (int i = e0 + tid; i < e1; i += 256) {
        int d = dst[i], s = src[i];
        int b = d >> 9;
        int slot = sex[b] + atomicAdd(&cur2[b], 1);
        stage[slot] = ((long long)(u32)d << 32) | (u32)s;
    }
    __syncthreads();
    const int tot = e1 - e0;
    for (int i = tid; i < tot; i += 256) {
        long long ll = stage[i];
        int b = (int)((u64)ll >> 32) >> 9;
        ebuf[(size_t)base[b] + (i - sex[b])] = ll;
    }
}

__global__ __launch_bounds__(256) void part2(const int* __restrict__ rowptr,
                                             const long long* __restrict__ ebuf,
                                             int* __restrict__ csrc) {
    __shared__ int nb[NPB], cnt[NPB];
    __shared__ int stage[CAPB];
    const int tid = threadIdx.x;
    const int n0 = blockIdx.x << 9;
    const int nn = min(NPB, NN - n0);
    const int estart = rowptr[n0];
    const int eend = rowptr[n0 + nn];
    const int tot = eend - estart;
    for (int i = tid; i < nn; i += 256) {
        nb[i] = rowptr[n0 + i] - estart;
        cnt[i] = 0;
    }
    __syncthreads();
    if (tot <= CAPB) {
        for (int i = estart + tid; i < eend; i += 256) {
            long long ll = ebuf[i];
            int ln = (int)((u64)ll >> 32) - n0;
            int pos = nb[ln] + atomicAdd(&cnt[ln], 1);
            stage[pos] = (int)ll;
        }
        __syncthreads();
        for (int i = tid; i < tot; i += 256) csrc[estart + i] = stage[i];
    } else {
        for (int i = estart + tid; i < eend; i += 256) {
            long long ll = ebuf[i];
            int ln = (int)((u64)ll >> 32) - n0;
            int pos = nb[ln] + atomicAdd(&cnt[ln], 1);
            csrc[estart + pos] = (int)ll;
        }
    }
}

// ============================== weight prep (fused 3 layers) ==============================

__global__ void transW3(const float* __restrict__ W1, u16* __restrict__ W1t,
                        const float* __restrict__ W2, u16* __restrict__ W2t,
                        const float* __restrict__ W3, u16* __restrict__ W3t) {
    int idx = blockIdx.x * 256 + threadIdx.x;
    if (idx < 32768) {                    // W1: K=256, Nin=128, pad 128
        int n = idx / 256, k = idx % 256;
        W1t[idx] = f2b(W1[(size_t)k * 128 + n]);
    } else if (idx < 32768 + 16384) {     // W2: K=128, Nin=128
        int j = idx - 32768;
        int n = j / 128, k = j % 128;
        W2t[j] = f2b(W2[(size_t)k * 128 + n]);
    } else if (idx < 32768 + 16384 + 6144) {  // W3: K=128, Nin=40, pad 48
        int j = idx - 32768 - 16384;
        int n = j / 128, k = j % 128;
        W3t[j] = f2b((n < 40) ? W3[(size_t)k * 40 + n] : 0.f);
    }
}

// ============================== MFMA GEMM: K-chunked B-in-LDS, pipelined A ==============================
// C[M,OUTW](bf16) = A[M,K] * Wt[NT*16,K]^T.  BM=128, 4 waves x 32 rows.
// B staged per 128-K chunk (<=32KB LDS -> 4+ blocks/CU). A frags global->reg,
// next-ks load issued before current MFMAs (named regs, static pipeline).
template<int K, int NT, int OUTW, bool AF32, int NH>
__global__ __launch_bounds__(256, 4) void gemm_ks(const void* __restrict__ Ap_,
                                                  const u16* __restrict__ Wt,
                                                  const float* __restrict__ al,
                                                  const float* __restrict__ ar,
                                                  u16* __restrict__ C,
                                                  float* __restrict__ el,
                                                  float* __restrict__ er, int M) {
    constexpr int KC = 128;              // K-chunk
    constexpr int NKC = K / KC;          // 1 or 2
    constexpr int NKS = KC / 32;         // 4 MFMA k-steps per chunk
    constexpr int NB = NT * 16;
    constexpr int CHK = KC / 8;          // 16B chunks per B row per K-chunk
    __shared__ u16 lB[NB * KC];          // chunk c stored at c^(row&7)
    const int tid = threadIdx.x;
    const int w = tid >> 6, l = tid & 63;
    const int lr = l & 15, lq = l >> 4;
    const u16* Ab = (const u16*)Ap_;
    const float* Af = (const float*)Ap_;

    const int row0 = blockIdx.x * 128 + w * 32;
    size_t aoff[2];
    #pragma unroll
    for (int mr = 0; mr < 2; ++mr) {
        int gr = row0 + mr * 16 + lr;
        if (gr >= M) gr = M - 1;
        aoff[mr] = (size_t)gr * K;
    }

    auto loadA1 = [&](int kc, int ks) -> bf16x8 {
        const int kk = kc * KC + ks * 32 + lq * 8;
        if (AF32) {
            float4 v0 = *reinterpret_cast<const float4*>(&Af[aoff[0] + kk]);
            float4 v1 = *reinterpret_cast<const float4*>(&Af[aoff[0] + kk + 4]);
            bf16x8 a;
            a[0] = (short)f2b(v0.x); a[1] = (short)f2b(v0.y);
            a[2] = (short)f2b(v0.z); a[3] = (short)f2b(v0.w);
            a[4] = (short)f2b(v1.x); a[5] = (short)f2b(v1.y);
            a[6] = (short)f2b(v1.z); a[7] = (short)f2b(v1.w);
            return a;
        }
        return *reinterpret_cast<const bf16x8*>(&Ab[aoff[0] + kk]);
    };
    auto loadA2 = [&](int kc, int ks) -> bf16x8 {
        const int kk = kc * KC + ks * 32 + lq * 8;
        if (AF32) {
            float4 v0 = *reinterpret_cast<const float4*>(&Af[aoff[1] + kk]);
            float4 v1 = *reinterpret_cast<const float4*>(&Af[aoff[1] + kk + 4]);
            bf16x8 a;
            a[0] = (short)f2b(v0.x); a[1] = (short)f2b(v0.y);
            a[2] = (short)f2b(v0.z); a[3] = (short)f2b(v0.w);
            a[4] = (short)f2b(v1.x); a[5] = (short)f2b(v1.y);
            a[6] = (short)f2b(v1.z); a[7] = (short)f2b(v1.w);
            return a;
        }
        return *reinterpret_cast<const bf16x8*>(&Ab[aoff[1] + kk]);
    };

    f32x4 acc[2][NT] = {};
    #pragma unroll
    for (int kc = 0; kc < NKC; ++kc) {
        // ---- stage B chunk (coalesced read, swizzled LDS write) ----
        for (int idx = tid; idx < NB * CHK; idx += 256) {
            int row = idx / CHK, c = idx % CHK;
            float4 v = *reinterpret_cast<const float4*>(&Wt[(size_t)row * K + kc * KC + c * 8]);
            int cs = c ^ (row & 7);
            *reinterpret_cast<float4*>(&lB[row * KC + cs * 8]) = v;
        }
        __syncthreads();
        // ---- pipelined K-steps ----
        bf16x8 aF0 = loadA1(kc, 0);
        bf16x8 aF1 = loadA2(kc, 0);
        #pragma unroll
        for (int ks = 0; ks < NKS; ++ks) {
            bf16x8 aN0, aN1;
            if (ks + 1 < NKS) {
                aN0 = loadA1(kc, ks + 1);
                aN1 = loadA2(kc, ks + 1);
            }
            const int cs = (ks * 4 + lq) ^ (lr & 7);
            #pragma unroll
            for (int nr = 0; nr < NT; ++nr) {
                bf16x8 bF = *reinterpret_cast<const bf16x8*>(&lB[(nr * 16 + lr) * KC + cs * 8]);
                acc[0][nr] = __builtin_amdgcn_mfma_f32_16x16x32_bf16(aF0, bF, acc[0][nr], 0, 0, 0);
                acc[1][nr] = __builtin_amdgcn_mfma_f32_16x16x32_bf16(aF1, bF, acc[1][nr], 0, 0, 0);
            }
            if (ks + 1 < NKS) { aF0 = aN0; aF1 = aN1; }
        }
        if (kc + 1 < NKC) __syncthreads();
    }

    // ---- epilogue: C store + fused el/er (C/D layout: col=lr, row=lq*4+reg [m89]) ----
    float alv[NT], arv[NT];
    #pragma unroll
    for (int nr = 0; nr < NT; ++nr) {
        int c = nr * 16 + lr;
        alv[nr] = (c < OUTW) ? al[c] : 0.f;
        arv[nr] = (c < OUTW) ? ar[c] : 0.f;
    }
    #pragma unroll
    for (int mr = 0; mr < 2; ++mr) {
        #pragma unroll
        for (int reg = 0; reg < 4; ++reg) {
            int gr = row0 + mr * 16 + lq * 4 + reg;
            bool ok = gr < M;
            if (ok) {
                #pragma unroll
                for (int nr = 0; nr < NT; ++nr) {
                    int gc = nr * 16 + lr;
                    if (gc < OUTW) C[(size_t)gr * OUTW + gc] = f2b(acc[mr][nr][reg]);
                }
            }
            float pl[NH] = {}, pr[NH] = {};
            #pragma unroll
            for (int nr = 0; nr < NT; ++nr) {
                int hidx = (NH == 1) ? 0 : (nr >> 1);
                pl[hidx] = fmaf(acc[mr][nr][reg], alv[nr], pl[hidx]);
                pr[hidx] = fmaf(acc[mr][nr][reg], arv[nr], pr[hidx]);
            }
            #pragma unroll
            for (int o = 8; o >= 1; o >>= 1) {
                #pragma unroll
                for (int hh = 0; hh < NH; ++hh) {
                    pl[hh] += __shfl_xor(pl[hh], o);
                    pr[hh] += __shfl_xor(pr[hh], o);
                }
            }
            if (ok && lr == 0) {
                #pragma unroll
                for (int hh = 0; hh < NH; ++hh) {
                    el[gr * NH + hh] = pl[hh];
                    er[gr * NH + hh] = pr[hh];
                }
            }
        }
    }
}

// ============================== aggregation v5 ==============================

template<bool RELU>
__global__ __launch_bounds__(256) void agg4v5(const char* __restrict__ hbase,  // h [N][64] dwords
                                              const float4* __restrict__ el4,
                                              const float4* __restrict__ er4,
                                              const float* __restrict__ bias,
                                              const int* __restrict__ rowptr,
                                              const int* __restrict__ csrc,
                                              u32* __restrict__ out, int N) {
    __shared__ u32 s_ed[4][CAP][8];      // [w0,so, w1,so, w2,so, w3,so]
    const int wslot = threadIdx.x >> 6, lane = threadIdx.x & 63;
    const int wid = blockIdx.x * 4 + wslot;
    if (wid >= N) return;
    const int beg = rowptr[wid];
    const int deg = rowptr[wid + 1] - beg;
    const float4 er = er4[wid];
    const int hh = lane >> 4;
    const u32 lshl = (u32)(lane << 2);
    const float2 bv = reinterpret_cast<const float2*>(bias)[lane];
    float accA, accB, invs;

    if (deg <= CAP) {
        for (int basej = 0; basej < deg; basej += 64) {
            int j = basej + lane;
            if (j < deg) {
                int sid = csrc[beg + j];
                float4 ev = el4[sid];
                float e0 = ev.x + er.x; e0 = e0 > 0.f ? e0 : 0.2f * e0;
                float e1 = ev.y + er.y; e1 = e1 > 0.f ? e1 : 0.2f * e1;
                float e2 = ev.z + er.z; e2 = e2 > 0.f ? e2 : 0.2f * e2;
                float e3 = ev.w + er.w; e3 = e3 > 0.f ? e3 : 0.2f * e3;
                u32 so = (u32)sid << 8;
                int2 v0 = make_int2(__float_as_int(__expf(e0)), (int)so);
                int2 v1 = make_int2(__float_as_int(__expf(e1)), (int)so);
                int2 v2 = make_int2(__float_as_int(__expf(e2)), (int)so);
                int2 v3 = make_int2(__float_as_int(__expf(e3)), (int)so);
                *reinterpret_cast<int2*>(&s_ed[wslot][j][0]) = v0;
                *reinterpret_cast<int2*>(&s_ed[wslot][j][2]) = v1;
                *reinterpret_cast<int2*>(&s_ed[wslot][j][4]) = v2;
                *reinterpret_cast<int2*>(&s_ed[wslot][j][6]) = v3;
            }
        }
        const u32* ebase = &s_ed[wslot][0][hh * 2];
        float a[8] = {}, b[8] = {}, sw[8] = {};
        int p = 0;
        const int deg8 = deg & ~7;
        for (; p < deg8; p += 8) {
            #pragma unroll
            for (int k = 0; k < 8; ++k) {
                int2 rv = *reinterpret_cast<const int2*>(ebase + (p + k) * 8);
                float wg = __int_as_float(rv.x);
                u32 hv = *reinterpret_cast<const u32*>(hbase + ((u32)rv.y | lshl));
                a[k] = fmaf(wg, bflo(hv), a[k]);
                b[k] = fmaf(wg, bfhi(hv), b[k]);
                sw[k] += wg;
            }
        }
        for (; p < deg; ++p) {
            int2 rv = *reinterpret_cast<const int2*>(ebase + p * 8);
            float wg = __int_as_float(rv.x);
            u32 hv = *reinterpret_cast<const u32*>(hbase + ((u32)rv.y | lshl));
            a[0] = fmaf(wg, bflo(hv), a[0]);
            b[0] = fmaf(wg, bfhi(hv), b[0]);
            sw[0] += wg;
        }
        accA = ((a[0] + a[1]) + (a[2] + a[3])) + ((a[4] + a[5]) + (a[6] + a[7]));
        accB = ((b[0] + b[1]) + (b[2] + b[3])) + ((b[4] + b[5]) + (b[6] + b[7]));
        float s = ((sw[0] + sw[1]) + (sw[2] + sw[3])) + ((sw[4] + sw[5]) + (sw[6] + sw[7]));
        invs = (deg > 0) ? 1.f / s : 0.f;
    } else {
        float er_h = hh == 0 ? er.x : hh == 1 ? er.y : hh == 2 ? er.z : er.w;
        float s = 0.f;
        accA = 0.f; accB = 0.f;
        for (int q = beg; q < beg + deg; ++q) {
            int sid = csrc[q];
            float4 ev = el4[sid];
            float e = (hh == 0 ? ev.x : hh == 1 ? ev.y : hh == 2 ? ev.z : ev.w) + er_h;
            e = e > 0.f ? e : 0.2f * e;
            float pe = __expf(e);
            u32 hv = *reinterpret_cast<const u32*>(hbase + (((u32)sid << 8) | lshl));
            s += pe;
            accA = fmaf(pe, bflo(hv), accA);
            accB = fmaf(pe, bfhi(hv), accB);
        }
        invs = 1.f / s;
    }
    float oA = accA * invs + bv.x;
    float oB = accB * invs + bv.y;
    if (RELU) { oA = fmaxf(oA, 0.f); oB = fmaxf(oB, 0.f); }
    out[(size_t)wid * 64 + lane] = ((u32)f2b(oB) << 16) | (u32)f2b(oA);
}

// single head + bias + log_softmax(40); h3 [N,40] bf16
__global__ __launch_bounds__(256) void agg1v5(const char* __restrict__ hbase,
                                              const float* __restrict__ el,
                                              const float* __restrict__ er,
                                              const float* __restrict__ bias,
                                              const int* __restrict__ rowptr,
                                              const int* __restrict__ csrc,
                                              float* __restrict__ out, int N) {
    __shared__ u32 s_ed[4][CAP][2];      // {w, sid*80}
    const int wslot = threadIdx.x >> 6, lane = threadIdx.x & 63;
    const int wid = blockIdx.x * 4 + wslot;
    if (wid >= N) return;
    const int beg = rowptr[wid];
    const int deg = rowptr[wid + 1] - beg;
    const float ern = er[wid];
    const int ll = lane < 40 ? lane : 39;
    const u32 lloff = (u32)(ll << 1);
    float acc, invs;

    if (deg <= CAP) {
        for (int basej = 0; basej < deg; basej += 64) {
            int j = basej + lane;
            if (j < deg) {
                int sid = csrc[beg + j];
                float e = el[sid] + ern; e = e > 0.f ? e : 0.2f * e;
                u32 so = (u32)sid * 80u;
                *reinterpret_cast<int2*>(&s_ed[wslot][j][0]) =
                    make_int2(__float_as_int(__expf(e)), (int)so);
            }
        }
        const u32* ebase = &s_ed[wslot][0][0];
        float a[8] = {}, sw[8] = {};
        int p = 0;
        const int deg8 = deg & ~7;
        for (; p < deg8; p += 8) {
            #pragma unroll
            for (int k = 0; k < 8; ++k) {
                int2 rv = *reinterpret_cast<const int2*>(ebase + (p + k) * 2);
                float wg = __int_as_float(rv.x);
                u16 hv = *reinterpret_cast<const u16*>(hbase + ((u32)rv.y + lloff));
                a[k] = fmaf(wg, b2f(hv), a[k]);
                sw[k] += wg;
            }
        }
        for (; p < deg; ++p) {
            int2 rv = *reinterpret_cast<const int2*>(ebase + p * 2);
            float wg = __int_as_float(rv.x);
            u16 hv = *reinterpret_cast<const u16*>(hbase + ((u32)rv.y + lloff));
            a[0] = fmaf(wg, b2f(hv), a[0]);
            sw[0] += wg;
        }
        acc = ((a[0] + a[1]) + (a[2] + a[3])) + ((a[4] + a[5]) + (a[6] + a[7]));
        float s = ((sw[0] + sw[1]) + (sw[2] + sw[3])) + ((sw[4] + sw[5]) + (sw[6] + sw[7]));
        invs = (deg > 0) ? 1.f / s : 0.f;
    } else {
        float s = 0.f;
        acc = 0.f;
        for (int q = beg; q < beg + deg; ++q) {
            int sid = csrc[q];
            float e = el[sid] + ern; e = e > 0.f ? e : 0.2f * e;
            float pe = __expf(e);
            u16 hv = *reinterpret_cast<const u16*>(hbase + ((u32)sid * 80u + lloff));
            s += pe;
            acc = fmaf(pe, b2f(hv), acc);
        }
        invs = 1.f / s;
    }
    float v = acc * invs + ((lane < 40) ? bias[lane] : 0.f);
    float vv = (lane < 40) ? v : -INFINITY;
    float mx = vv;
    #pragma unroll
    for (int o = 32; o >= 1; o >>= 1) mx = fmaxf(mx, __shfl_xor(mx, o));
    float ex = (lane < 40) ? __expf(v - mx) : 0.f;
    float se = ex;
    #pragma unroll
    for (int o = 32; o >= 1; o >>= 1) se += __shfl_xor(se, o);
    if (lane < 40) out[(size_t)wid * 40 + lane] = v - mx - logf(se);
}

// ============================== launch ==============================

extern "C" void kernel_launch(void* const* d_in, const int* in_sizes, int n_in,
                              void* d_out, int out_size, void* d_ws, size_t ws_size,
                              hipStream_t stream) {
    const float* feat = (const float*)d_in[0];
    const float* W1  = (const float*)d_in[1];
    const float* al1 = (const float*)d_in[2];
    const float* ar1 = (const float*)d_in[3];
    const float* b1  = (const float*)d_in[4];
    const float* W2  = (const float*)d_in[5];
    const float* al2 = (const float*)d_in[6];
    const float* ar2 = (const float*)d_in[7];
    const float* b2  = (const float*)d_in[8];
    const float* W3  = (const float*)d_in[9];
    const float* al3 = (const float*)d_in[10];
    const float* ar3 = (const float*)d_in[11];
    const float* b3  = (const float*)d_in[12];
    const int*   src = (const int*)d_in[13];
    const int*   dst = (const int*)d_in[14];
    float* out = (float*)d_out;
    const int N = NN, E = NE;

    char* ws = (char*)d_ws;
    size_t off = 0;
    auto alloc = [&](size_t bytes) -> char* {
        char* p = ws + off;
        off += (bytes + 255) & ~(size_t)255;
        return p;
    };
    int* deg    = (int*)alloc((size_t)N * 4);
    int* rowptr = (int*)alloc((size_t)(N + 1) * 4);
    int* bsum   = (int*)alloc(512 * 4);
    int* gcur   = (int*)alloc(256 * 4);
    int* csrc   = (int*)alloc((size_t)E * 4);
    long long* ebuf = (long long*)alloc((size_t)E * 8);
    float* el   = (float*)alloc((size_t)N * 4 * 4);
    float* er   = (float*)alloc((size_t)N * 4 * 4);
    u16* hb     = (u16*)alloc((size_t)N * 128 * 2);
    u16* xb     = (u16*)alloc((size_t)N * 128 * 2);
    u16* h3     = (u16*)alloc((size_t)N * 40 * 2 + 256);
    u16* W1t    = (u16*)alloc((size_t)128 * 256 * 2);
    u16* W2t    = (u16*)alloc((size_t)128 * 128 * 2);
    u16* W3t    = (u16*)alloc((size_t)48 * 128 * 2);

    // ---- CSR rowptr ----
    hipMemsetAsync(deg, 0, (size_t)N * 4, stream);
    hist_kernel<<<(E + 255) / 256, 256, 0, stream>>>(dst, deg, E);
    int NB = (N + 255) / 256;
    scan_local<<<NB, 256, 0, stream>>>(deg, rowptr, bsum, N);
    scan_bsum<<<1, 512, 0, stream>>>(bsum, NB);
    scan_add<<<(N + 255) / 256, 256, 0, stream>>>(rowptr, bsum, N);
    // ---- bucketed edge partition -> csrc ----
    initcur<<<1, 256, 0, stream>>>(rowptr, gcur);
    part1<<<P1B, 256, 0, stream>>>(src, dst, gcur, ebuf);
    part2<<<NBUC, 256, 0, stream>>>(rowptr, ebuf, csrc);

    // ---- weight prep (one kernel) ----
    transW3<<<(32768 + 16384 + 6144 + 255) / 256, 256, 0, stream>>>(W1, W1t, W2, W2t, W3, W3t);

    int gemmGrid = (N + 127) / 128;
    int nodeGrid = (N + 3) / 4;

    // ---- layer 1 ----
    gemm_ks<256, 8, 128, true, 4><<<gemmGrid, 256, 0, stream>>>(feat, W1t, al1, ar1, hb, el, er, N);
    agg4v5<true><<<nodeGrid, 256, 0, stream>>>((const char*)hb, (const float4*)el, (const float4*)er,
                                               b1, rowptr, csrc, (u32*)xb, N);

    // ---- layer 2 ----
    gemm_ks<128, 8, 128, false, 4><<<gemmGrid, 256, 0, stream>>>(xb, W2t, al2, ar2, hb, el, er, N);
    agg4v5<true><<<nodeGrid, 256, 0, stream>>>((const char*)hb, (const float4*)el, (const float4*)er,
                                               b2, rowptr, csrc, (u32*)xb, N);

    // ---- layer 3 (+ fused log_softmax) ----
    gemm_ks<128, 3, 40, false, 1><<<gemmGrid, 256, 0, stream>>>(xb, W3t, al3, ar3, h3, el, er, N);
    agg1v5<<<nodeGrid, 256, 0, stream>>>((const char*)h3, el, er, b3, rowptr, csrc, out, N);
}

// Round 10
// 330.731 us; speedup vs baseline: 1.3905x; 1.0234x over previous
//
#include <hip/hip_runtime.h>
#include <hip/hip_bf16.h>
#include <math.h>

#define NN 100000
#define NE 1000000
#define CAP 128
#define NPB 512                          // nodes per bucket (pow2, shift 9)
#define NBUC ((NN + NPB - 1) / NPB)      // 196
#define CAPB 8192                        // max staged edges per bucket
#define P1B 512                          // part1 blocks
#define P1E ((NE + P1B - 1) / P1B)       // 1954 edges per part1 block

typedef __attribute__((ext_vector_type(8))) short bf16x8;
typedef __attribute__((ext_vector_type(4))) float f32x4;
typedef unsigned int u32;
typedef unsigned short u16;
typedef unsigned long long u64;

__device__ __forceinline__ u16 f2b(float f) {
    __hip_bfloat16 h = __float2bfloat16(f);
    return *reinterpret_cast<u16*>(&h);
}
__device__ __forceinline__ float b2f(u16 u) {
    __hip_bfloat16 h = *reinterpret_cast<__hip_bfloat16*>(&u);
    return __bfloat162float(h);
}
__device__ __forceinline__ float bflo(u32 v) { return __uint_as_float(v << 16); }
__device__ __forceinline__ float bfhi(u32 v) { return __uint_as_float(v & 0xffff0000u); }

// ============================== CSR: degree + rowptr ==============================

__global__ void hist_kernel(const int* __restrict__ dst, int* __restrict__ deg, int E) {
    int i = blockIdx.x * blockDim.x + threadIdx.x;
    if (i < E) atomicAdd(&deg[dst[i]], 1);
}

__global__ void scan_local(const int* __restrict__ deg, int* __restrict__ rowptr,
                           int* __restrict__ bsum, int N) {
    __shared__ int s[256];
    int i = blockIdx.x * 256 + threadIdx.x;
    int v = (i < N) ? deg[i] : 0;
    s[threadIdx.x] = v;
    __syncthreads();
    #pragma unroll
    for (int off = 1; off < 256; off <<= 1) {
        int t = (threadIdx.x >= off) ? s[threadIdx.x - off] : 0;
        __syncthreads();
        s[threadIdx.x] += t;
        __syncthreads();
    }
    if (i < N) rowptr[i + 1] = s[threadIdx.x];
    if (threadIdx.x == 255) bsum[blockIdx.x] = s[255];
}

__global__ void scan_bsum(int* __restrict__ bsum, int NB) {
    __shared__ int s[512];
    int v = (threadIdx.x < NB) ? bsum[threadIdx.x] : 0;
    s[threadIdx.x] = v;
    __syncthreads();
    for (int off = 1; off < 512; off <<= 1) {
        int t = (threadIdx.x >= off) ? s[threadIdx.x - off] : 0;
        __syncthreads();
        s[threadIdx.x] += t;
        __syncthreads();
    }
    if (threadIdx.x < NB) bsum[threadIdx.x] = s[threadIdx.x] - v;  // exclusive
}

__global__ void scan_add(int* __restrict__ rowptr, const int* __restrict__ bsum, int N) {
    int i = blockIdx.x * blockDim.x + threadIdx.x;
    if (i < N) rowptr[i + 1] += bsum[i >> 8];
    if (i == 0) rowptr[0] = 0;
}

// ============================== CSR: bucketed edge partition ==============================

__global__ void initcur(const int* __restrict__ rowptr, int* __restrict__ gcur) {
    int b = threadIdx.x;
    if (b < NBUC) gcur[b] = rowptr[b << 9];
}

__global__ __launch_bounds__(256) void part1(const int* __restrict__ src,
                                             const int* __restrict__ dst,
                                             int* __restrict__ gcur,
                                             long long* __restrict__ ebuf) {
    __shared__ int cnt[256], sex[256], base[256], cur2[256], scn[256];
    __shared__ long long stage[P1E];
    const int tid = threadIdx.x;
    const int e0 = blockIdx.x * P1E;
    const int e1 = min(e0 + P1E, NE);
    cnt[tid] = 0;
    __syncthreads();
    for (int i = e0 + tid; i < e1; i += 256)
        atomicAdd(&cnt[dst[i] >> 9], 1);
    __syncthreads();
    int v = cnt[tid];
    scn[tid] = v;
    __syncthreads();
    #pragma unroll
    for (int off = 1; off < 256; off <<= 1) {
        int t = (tid >= off) ? scn[tid - off] : 0;
        __syncthreads();
        scn[tid] += t;
        __syncthreads();
    }
    sex[tid] = scn[tid] - v;  // exclusive scan
    if (tid < NBUC) base[tid] = (v > 0) ? atomicAdd(&gcur[tid], v) : 0;
    cur2[tid] = 0;
    __syncthreads();
    for (int i = e0 + tid; i < e1; i += 256) {
        int d = dst[i], s = src[i];
        int b = d >> 9;
        int slot = sex[b] + atomicAdd(&cur2[b], 1);
        stage[slot] = ((long long)(u32)d << 32) | (u32)s;
    }
    __syncthreads();
    const int tot = e1 - e0;
    for (int i = tid; i < tot; i += 256) {
        long long ll = stage[i];
        int b = (int)((u64)ll >> 32) >> 9;
        ebuf[(size_t)base[b] + (i - sex[b])] = ll;
    }
}

__global__ __launch_bounds__(256) void part2(const int* __restrict__ rowptr,
                                             const long long* __restrict__ ebuf,
                                             int* __restrict__ csrc) {
    __shared__ int nb[NPB], cnt[NPB];
    __shared__ int stage[CAPB];
    const int tid = threadIdx.x;
    const int n0 = blockIdx.x << 9;
    const int nn = min(NPB, NN - n0);
    const int estart = rowptr[n0];
    const int eend = rowptr[n0 + nn];
    const int tot = eend - estart;
    for (int i = tid; i < nn; i += 256) {
        nb[i] = rowptr[n0 + i] - estart;
        cnt[i] = 0;
    }
    __syncthreads();
    if (tot <= CAPB) {
        for (int i = estart + tid; i < eend; i += 256) {
            long long ll = ebuf[i];
            int ln = (int)((u64)ll >> 32) - n0;
            int pos = nb[ln] + atomicAdd(&cnt[ln], 1);
            stage[pos] = (int)ll;
        }
        __syncthreads();
        for (int i = tid; i < tot; i += 256) csrc[estart + i] = stage[i];
    } else {
        for (int i = estart + tid; i < eend; i += 256) {
            long long ll = ebuf[i];
            int ln = (int)((u64)ll >> 32) - n0;
            int pos = nb[ln] + atomicAdd(&cnt[ln], 1);
            csrc[estart + pos] = (int)ll;
        }
    }
}

// ============================== weight prep (fused 3 layers) ==============================

__global__ void transW3(const float* __restrict__ W1, u16* __restrict__ W1t,
                        const float* __restrict__ W2, u16* __restrict__ W2t,
                        const float* __restrict__ W3, u16* __restrict__ W3t) {
    int idx = blockIdx.x * 256 + threadIdx.x;
    if (idx < 32768) {                    // W1: K=256, Nin=128, pad 128
        int n = idx / 256, k = idx % 256;
        W1t[idx] = f2b(W1[(size_t)k * 128 + n]);
    } else if (idx < 32768 + 16384) {     // W2: K=128, Nin=128
        int j = idx - 32768;
        int n = j / 128, k = j % 128;
        W2t[j] = f2b(W2[(size_t)k * 128 + n]);
    } else if (idx < 32768 + 16384 + 6144) {  // W3: K=128, Nin=40, pad 48
        int j = idx - 32768 - 16384;
        int n = j / 128, k = j % 128;
        W3t[j] = f2b((n < 40) ? W3[(size_t)k * 40 + n] : 0.f);
    }
}

// ============================== MFMA GEMM v3: occupancy-first streaming ==============================
// C[M,OUTW](bf16) = A[M,K] * Wt[NT*16,K]^T.  BM=64, 4 waves x 16 rows (1 m-frag/wave).
// B staged per 128-K chunk into LDS (swizzled; NT=8 -> 32KB). A: full-chunk burst
// global->reg (4 bf16x8 or 8 float4+cvt, all independent -> deep VMEM pipeline).
// Epilogue fuses el/er.
template<int K, int NT, int OUTW, bool AF32, int NH>
__global__ __launch_bounds__(256, 4) void gemm_s(const void* __restrict__ Ap_,
                                                 const u16* __restrict__ Wt,
                                                 const float* __restrict__ al,
                                                 const float* __restrict__ ar,
                                                 u16* __restrict__ C,
                                                 float* __restrict__ el,
                                                 float* __restrict__ er, int M) {
    constexpr int KC = 128;              // K-chunk
    constexpr int NKC = K / KC;          // 1 or 2
    constexpr int NB = NT * 16;
    constexpr int CHK = KC / 8;          // 16 x 16B chunks per B row
    __shared__ u16 lB[NB * KC];          // chunk c of row stored at c^(row&7)
    const int tid = threadIdx.x;
    const int w = tid >> 6, l = tid & 63;
    const int lr = l & 15, lq = l >> 4;
    const int row0 = blockIdx.x * 64 + w * 16;
    const u16* Ab = (const u16*)Ap_;
    const float* Af = (const float*)Ap_;

    int gr0 = row0 + lr; if (gr0 >= M) gr0 = M - 1;
    const size_t aoff = (size_t)gr0 * K;

    f32x4 acc[NT] = {};
    #pragma unroll
    for (int kc = 0; kc < NKC; ++kc) {
        // ---- stage B chunk (coalesced read, swizzled LDS write) ----
        for (int idx = tid; idx < NB * CHK; idx += 256) {
            int row = idx / CHK, c = idx % CHK;
            float4 v = *reinterpret_cast<const float4*>(&Wt[(size_t)row * K + kc * KC + c * 8]);
            int cs = c ^ (row & 7);
            *reinterpret_cast<float4*>(&lB[row * KC + cs * 8]) = v;
        }
        __syncthreads();
        // ---- A burst: entire K-chunk for this wave's row, independent loads ----
        bf16x8 a0, a1, a2, a3;
        if (AF32) {
            float4 v[8];
            #pragma unroll
            for (int i = 0; i < 8; ++i)
                v[i] = *reinterpret_cast<const float4*>(
                    &Af[aoff + kc * KC + (i >> 1) * 32 + lq * 8 + (i & 1) * 4]);
            bf16x8 t[4];
            #pragma unroll
            for (int i = 0; i < 4; ++i) {
                t[i][0] = (short)f2b(v[2 * i].x); t[i][1] = (short)f2b(v[2 * i].y);
                t[i][2] = (short)f2b(v[2 * i].z); t[i][3] = (short)f2b(v[2 * i].w);
                t[i][4] = (short)f2b(v[2 * i + 1].x); t[i][5] = (short)f2b(v[2 * i + 1].y);
                t[i][6] = (short)f2b(v[2 * i + 1].z); t[i][7] = (short)f2b(v[2 * i + 1].w);
            }
            a0 = t[0]; a1 = t[1]; a2 = t[2]; a3 = t[3];
        } else {
            a0 = *reinterpret_cast<const bf16x8*>(&Ab[aoff + kc * KC + 0 * 32 + lq * 8]);
            a1 = *reinterpret_cast<const bf16x8*>(&Ab[aoff + kc * KC + 1 * 32 + lq * 8]);
            a2 = *reinterpret_cast<const bf16x8*>(&Ab[aoff + kc * KC + 2 * 32 + lq * 8]);
            a3 = *reinterpret_cast<const bf16x8*>(&Ab[aoff + kc * KC + 3 * 32 + lq * 8]);
        }
        // ---- 4 MFMA k-steps ----
        #pragma unroll
        for (int ks = 0; ks < 4; ++ks) {
            bf16x8 aF = (ks == 0) ? a0 : (ks == 1) ? a1 : (ks == 2) ? a2 : a3;
            const int cs = (ks * 4 + lq) ^ (lr & 7);
            #pragma unroll
            for (int nr = 0; nr < NT; ++nr) {
                bf16x8 bF = *reinterpret_cast<const bf16x8*>(&lB[(nr * 16 + lr) * KC + cs * 8]);
                acc[nr] = __builtin_amdgcn_mfma_f32_16x16x32_bf16(aF, bF, acc[nr], 0, 0, 0);
            }
        }
        if (kc + 1 < NKC) __syncthreads();
    }

    // ---- epilogue: C store + fused el/er (C/D layout: col=lr, row=lq*4+reg [m89]) ----
    float alv[NT], arv[NT];
    #pragma unroll
    for (int nr = 0; nr < NT; ++nr) {
        int c = nr * 16 + lr;
        alv[nr] = (c < OUTW) ? al[c] : 0.f;
        arv[nr] = (c < OUTW) ? ar[c] : 0.f;
    }
    #pragma unroll
    for (int reg = 0; reg < 4; ++reg) {
        int gr = row0 + lq * 4 + reg;
        bool ok = gr < M;
        if (ok) {
            #pragma unroll
            for (int nr = 0; nr < NT; ++nr) {
                int gc = nr * 16 + lr;
                if (gc < OUTW) C[(size_t)gr * OUTW + gc] = f2b(acc[nr][reg]);
            }
        }
        float pl[NH] = {}, pr[NH] = {};
        #pragma unroll
        for (int nr = 0; nr < NT; ++nr) {
            int hidx = (NH == 1) ? 0 : (nr >> 1);
            pl[hidx] = fmaf(acc[nr][reg], alv[nr], pl[hidx]);
            pr[hidx] = fmaf(acc[nr][reg], arv[nr], pr[hidx]);
        }
        #pragma unroll
        for (int o = 8; o >= 1; o >>= 1) {
            #pragma unroll
            for (int hh = 0; hh < NH; ++hh) {
                pl[hh] += __shfl_xor(pl[hh], o);
                pr[hh] += __shfl_xor(pr[hh], o);
            }
        }
        if (ok && lr == 0) {
            #pragma unroll
            for (int hh = 0; hh < NH; ++hh) {
                el[gr * NH + hh] = pl[hh];
                er[gr * NH + hh] = pr[hh];
            }
        }
    }
}

// ============================== aggregation v5 ==============================

template<bool RELU>
__global__ __launch_bounds__(256) void agg4v5(const char* __restrict__ hbase,  // h [N][64] dwords
                                              const float4* __restrict__ el4,
                                              const float4* __restrict__ er4,
                                              const float* __restrict__ bias,
                                              const int* __restrict__ rowptr,
                                              const int* __restrict__ csrc,
                                              u32* __restrict__ out, int N) {
    __shared__ u32 s_ed[4][CAP][8];      // [w0,so, w1,so, w2,so, w3,so]
    const int wslot = threadIdx.x >> 6, lane = threadIdx.x & 63;
    const int wid = blockIdx.x * 4 + wslot;
    if (wid >= N) return;
    const int beg = rowptr[wid];
    const int deg = rowptr[wid + 1] - beg;
    const float4 er = er4[wid];
    const int hh = lane >> 4;
    const u32 lshl = (u32)(lane << 2);
    const float2 bv = reinterpret_cast<const float2*>(bias)[lane];
    float accA, accB, invs;

    if (deg <= CAP) {
        for (int basej = 0; basej < deg; basej += 64) {
            int j = basej + lane;
            if (j < deg) {
                int sid = csrc[beg + j];
                float4 ev = el4[sid];
                float e0 = ev.x + er.x; e0 = e0 > 0.f ? e0 : 0.2f * e0;
                float e1 = ev.y + er.y; e1 = e1 > 0.f ? e1 : 0.2f * e1;
                float e2 = ev.z + er.z; e2 = e2 > 0.f ? e2 : 0.2f * e2;
                float e3 = ev.w + er.w; e3 = e3 > 0.f ? e3 : 0.2f * e3;
                u32 so = (u32)sid << 8;
                int2 v0 = make_int2(__float_as_int(__expf(e0)), (int)so);
                int2 v1 = make_int2(__float_as_int(__expf(e1)), (int)so);
                int2 v2 = make_int2(__float_as_int(__expf(e2)), (int)so);
                int2 v3 = make_int2(__float_as_int(__expf(e3)), (int)so);
                *reinterpret_cast<int2*>(&s_ed[wslot][j][0]) = v0;
                *reinterpret_cast<int2*>(&s_ed[wslot][j][2]) = v1;
                *reinterpret_cast<int2*>(&s_ed[wslot][j][4]) = v2;
                *reinterpret_cast<int2*>(&s_ed[wslot][j][6]) = v3;
            }
        }
        const u32* ebase = &s_ed[wslot][0][hh * 2];
        float a[8] = {}, b[8] = {}, sw[8] = {};
        int p = 0;
        const int deg8 = deg & ~7;
        for (; p < deg8; p += 8) {
            #pragma unroll
            for (int k = 0; k < 8; ++k) {
                int2 rv = *reinterpret_cast<const int2*>(ebase + (p + k) * 8);
                float wg = __int_as_float(rv.x);
                u32 hv = *reinterpret_cast<const u32*>(hbase + ((u32)rv.y | lshl));
                a[k] = fmaf(wg, bflo(hv), a[k]);
                b[k] = fmaf(wg, bfhi(hv), b[k]);
                sw[k] += wg;
            }
        }
        for (; p < deg; ++p) {
            int2 rv = *reinterpret_cast<const int2*>(ebase + p * 8);
            float wg = __int_as_float(rv.x);
            u32 hv = *reinterpret_cast<const u32*>(hbase + ((u32)rv.y | lshl));
            a[0] = fmaf(wg, bflo(hv), a[0]);
            b[0] = fmaf(wg, bfhi(hv), b[0]);
            sw[0] += wg;
        }
        accA = ((a[0] + a[1]) + (a[2] + a[3])) + ((a[4] + a[5]) + (a[6] + a[7]));
        accB = ((b[0] + b[1]) + (b[2] + b[3])) + ((b[4] + b[5]) + (b[6] + b[7]));
        float s = ((sw[0] + sw[1]) + (sw[2] + sw[3])) + ((sw[4] + sw[5]) + (sw[6] + sw[7]));
        invs = (deg > 0) ? 1.f / s : 0.f;
    } else {
        float er_h = hh == 0 ? er.x : hh == 1 ? er.y : hh == 2 ? er.z : er.w;
        float s = 0.f;
        accA = 0.f; accB = 0.f;
        for (int q = beg; q < beg + deg; ++q) {
            int sid = csrc[q];
            float4 ev = el4[sid];
            float e = (hh == 0 ? ev.x : hh == 1 ? ev.y : hh == 2 ? ev.z : ev.w) + er_h;
            e = e > 0.f ? e : 0.2f * e;
            float pe = __expf(e);
            u32 hv = *reinterpret_cast<const u32*>(hbase + (((u32)sid << 8) | lshl));
            s += pe;
            accA = fmaf(pe, bflo(hv), accA);
            accB = fmaf(pe, bfhi(hv), accB);
        }
        invs = 1.f / s;
    }
    float oA = accA * invs + bv.x;
    float oB = accB * invs + bv.y;
    if (RELU) { oA = fmaxf(oA, 0.f); oB = fmaxf(oB, 0.f); }
    out[(size_t)wid * 64 + lane] = ((u32)f2b(oB) << 16) | (u32)f2b(oA);
}

// single head + bias + log_softmax(40); h3 [N,40] bf16
__global__ __launch_bounds__(256) void agg1v5(const char* __restrict__ hbase,
                                              const float* __restrict__ el,
                                              const float* __restrict__ er,
                                              const float* __restrict__ bias,
                                              const int* __restrict__ rowptr,
                                              const int* __restrict__ csrc,
                                              float* __restrict__ out, int N) {
    __shared__ u32 s_ed[4][CAP][2];      // {w, sid*80}
    const int wslot = threadIdx.x >> 6, lane = threadIdx.x & 63;
    const int wid = blockIdx.x * 4 + wslot;
    if (wid >= N) return;
    const int beg = rowptr[wid];
    const int deg = rowptr[wid + 1] - beg;
    const float ern = er[wid];
    const int ll = lane < 40 ? lane : 39;
    const u32 lloff = (u32)(ll << 1);
    float acc, invs;

    if (deg <= CAP) {
        for (int basej = 0; basej < deg; basej += 64) {
            int j = basej + lane;
            if (j < deg) {
                int sid = csrc[beg + j];
                float e = el[sid] + ern; e = e > 0.f ? e : 0.2f * e;
                u32 so = (u32)sid * 80u;
                *reinterpret_cast<int2*>(&s_ed[wslot][j][0]) =
                    make_int2(__float_as_int(__expf(e)), (int)so);
            }
        }
        const u32* ebase = &s_ed[wslot][0][0];
        float a[8] = {}, sw[8] = {};
        int p = 0;
        const int deg8 = deg & ~7;
        for (; p < deg8; p += 8) {
            #pragma unroll
            for (int k = 0; k < 8; ++k) {
                int2 rv = *reinterpret_cast<const int2*>(ebase + (p + k) * 2);
                float wg = __int_as_float(rv.x);
                u16 hv = *reinterpret_cast<const u16*>(hbase + ((u32)rv.y + lloff));
                a[k] = fmaf(wg, b2f(hv), a[k]);
                sw[k] += wg;
            }
        }
        for (; p < deg; ++p) {
            int2 rv = *reinterpret_cast<const int2*>(ebase + p * 2);
            float wg = __int_as_float(rv.x);
            u16 hv = *reinterpret_cast<const u16*>(hbase + ((u32)rv.y + lloff));
            a[0] = fmaf(wg, b2f(hv), a[0]);
            sw[0] += wg;
        }
        acc = ((a[0] + a[1]) + (a[2] + a[3])) + ((a[4] + a[5]) + (a[6] + a[7]));
        float s = ((sw[0] + sw[1]) + (sw[2] + sw[3])) + ((sw[4] + sw[5]) + (sw[6] + sw[7]));
        invs = (deg > 0) ? 1.f / s : 0.f;
    } else {
        float s = 0.f;
        acc = 0.f;
        for (int q = beg; q < beg + deg; ++q) {
            int sid = csrc[q];
            float e = el[sid] + ern; e = e > 0.f ? e : 0.2f * e;
            float pe = __expf(e);
            u16 hv = *reinterpret_cast<const u16*>(hbase + ((u32)sid * 80u + lloff));
            s += pe;
            acc = fmaf(pe, b2f(hv), acc);
        }
        invs = 1.f / s;
    }
    float v = acc * invs + ((lane < 40) ? bias[lane] : 0.f);
    float vv = (lane < 40) ? v : -INFINITY;
    float mx = vv;
    #pragma unroll
    for (int o = 32; o >= 1; o >>= 1) mx = fmaxf(mx, __shfl_xor(mx, o));
    float ex = (lane < 40) ? __expf(v - mx) : 0.f;
    float se = ex;
    #pragma unroll
    for (int o = 32; o >= 1; o >>= 1) se += __shfl_xor(se, o);
    if (lane < 40) out[(size_t)wid * 40 + lane] = v - mx - logf(se);
}

// ============================== launch ==============================

extern "C" void kernel_launch(void* const* d_in, const int* in_sizes, int n_in,
                              void* d_out, int out_size, void* d_ws, size_t ws_size,
                              hipStream_t stream) {
    const float* feat = (const float*)d_in[0];
    const float* W1  = (const float*)d_in[1];
    const float* al1 = (const float*)d_in[2];
    const float* ar1 = (const float*)d_in[3];
    const float* b1  = (const float*)d_in[4];
    const float* W2  = (const float*)d_in[5];
    const float* al2 = (const float*)d_in[6];
    const float* ar2 = (const float*)d_in[7];
    const float* b2  = (const float*)d_in[8];
    const float* W3  = (const float*)d_in[9];
    const float* al3 = (const float*)d_in[10];
    const float* ar3 = (const float*)d_in[11];
    const float* b3  = (const float*)d_in[12];
    const int*   src = (const int*)d_in[13];
    const int*   dst = (const int*)d_in[14];
    float* out = (float*)d_out;
    const int N = NN, E = NE;

    char* ws = (char*)d_ws;
    size_t off = 0;
    auto alloc = [&](size_t bytes) -> char* {
        char* p = ws + off;
        off += (bytes + 255) & ~(size_t)255;
        return p;
    };
    int* deg    = (int*)alloc((size_t)N * 4);
    int* rowptr = (int*)alloc((size_t)(N + 1) * 4);
    int* bsum   = (int*)alloc(512 * 4);
    int* gcur   = (int*)alloc(256 * 4);
    int* csrc   = (int*)alloc((size_t)E * 4);
    long long* ebuf = (long long*)alloc((size_t)E * 8);
    float* el   = (float*)alloc((size_t)N * 4 * 4);
    float* er   = (float*)alloc((size_t)N * 4 * 4);
    u16* hb     = (u16*)alloc((size_t)N * 128 * 2);
    u16* xb     = (u16*)alloc((size_t)N * 128 * 2);
    u16* h3     = (u16*)alloc((size_t)N * 40 * 2 + 256);
    u16* W1t    = (u16*)alloc((size_t)128 * 256 * 2);
    u16* W2t    = (u16*)alloc((size_t)128 * 128 * 2);
    u16* W3t    = (u16*)alloc((size_t)48 * 128 * 2);

    // ---- CSR rowptr ----
    hipMemsetAsync(deg, 0, (size_t)N * 4, stream);
    hist_kernel<<<(E + 255) / 256, 256, 0, stream>>>(dst, deg, E);
    int NB = (N + 255) / 256;
    scan_local<<<NB, 256, 0, stream>>>(deg, rowptr, bsum, N);
    scan_bsum<<<1, 512, 0, stream>>>(bsum, NB);
    scan_add<<<(N + 255) / 256, 256, 0, stream>>>(rowptr, bsum, N);
    // ---- bucketed edge partition -> csrc ----
    initcur<<<1, 256, 0, stream>>>(rowptr, gcur);
    part1<<<P1B, 256, 0, stream>>>(src, dst, gcur, ebuf);
    part2<<<NBUC, 256, 0, stream>>>(rowptr, ebuf, csrc);

    // ---- weight prep (one kernel) ----
    transW3<<<(32768 + 16384 + 6144 + 255) / 256, 256, 0, stream>>>(W1, W1t, W2, W2t, W3, W3t);

    int gemmGrid = (N + 63) / 64;
    int nodeGrid = (N + 3) / 4;

    // ---- layer 1 ----
    gemm_s<256, 8, 128, true, 4><<<gemmGrid, 256, 0, stream>>>(feat, W1t, al1, ar1, hb, el, er, N);
    agg4v5<true><<<nodeGrid, 256, 0, stream>>>((const char*)hb, (const float4*)el, (const float4*)er,
                                               b1, rowptr, csrc, (u32*)xb, N);

    // ---- layer 2 ----
    gemm_s<128, 8, 128, false, 4><<<gemmGrid, 256, 0, stream>>>(xb, W2t, al2, ar2, hb, el, er, N);
    agg4v5<true><<<nodeGrid, 256, 0, stream>>>((const char*)hb, (const float4*)el, (const float4*)er,
                                               b2, rowptr, csrc, (u32*)xb, N);

    // ---- layer 3 (+ fused log_softmax) ----
    gemm_s<128, 3, 40, false, 1><<<gemmGrid, 256, 0, stream>>>(xb, W3t, al3, ar3, h3, el, er, N);
    agg1v5<<<nodeGrid, 256, 0, stream>>>((const char*)h3, el, er, b3, rowptr, csrc, out, N);
}

// Round 11
// 268.688 us; speedup vs baseline: 1.7116x; 1.2309x over previous
//
#include <hip/hip_runtime.h>
#include <hip/hip_bf16.h>
#include <math.h>

#define NN 100000
#define NE 1000000
#define NPB 512                          // nodes per bucket (pow2, shift 9)
#define NBUC ((NN + NPB - 1) / NPB)      // 196
#define CAPB 8192                        // max staged edges per bucket
#define P1B 512                          // part1 blocks
#define P1E ((NE + P1B - 1) / P1B)       // 1954 edges per part1 block
#define BCAP 512                         // max edges per 8-node agg block

typedef __attribute__((ext_vector_type(8))) short bf16x8;
typedef __attribute__((ext_vector_type(4))) float f32x4;
typedef unsigned int u32;
typedef unsigned short u16;
typedef unsigned long long u64;

__device__ __forceinline__ u16 f2b(float f) {
    __hip_bfloat16 h = __float2bfloat16(f);
    return *reinterpret_cast<u16*>(&h);
}
__device__ __forceinline__ float b2f(u16 u) {
    __hip_bfloat16 h = *reinterpret_cast<__hip_bfloat16*>(&u);
    return __bfloat162float(h);
}
__device__ __forceinline__ float bflo(u32 v) { return __uint_as_float(v << 16); }
__device__ __forceinline__ float bfhi(u32 v) { return __uint_as_float(v & 0xffff0000u); }

// ============================== CSR: bucket count + scan ==============================

__global__ void bucket_cnt(const int* __restrict__ dst, int* __restrict__ bcnt, int E) {
    __shared__ int c[NBUC];
    for (int i = threadIdx.x; i < NBUC; i += 256) c[i] = 0;
    __syncthreads();
    int i = blockIdx.x * 256 + threadIdx.x;
    const int stride = gridDim.x * 256;
    for (; i < E; i += stride) atomicAdd(&c[dst[i] >> 9], 1);
    __syncthreads();
    for (int j = threadIdx.x; j < NBUC; j += 256)
        if (c[j]) atomicAdd(&bcnt[j], c[j]);
}

__global__ void bucket_scan(const int* __restrict__ bcnt, int* __restrict__ bbase,
                            int* __restrict__ gcur) {
    __shared__ int s[256];
    const int tid = threadIdx.x;
    int v = (tid < NBUC) ? bcnt[tid] : 0;
    s[tid] = v;
    __syncthreads();
    for (int off = 1; off < 256; off <<= 1) {
        int t = (tid >= off) ? s[tid - off] : 0;
        __syncthreads();
        s[tid] += t;
        __syncthreads();
    }
    if (tid < NBUC) {
        int excl = s[tid] - v;
        bbase[tid] = excl;
        gcur[tid] = excl;
    }
    if (tid == NBUC - 1) bbase[NBUC] = s[tid];
}

// ============================== CSR: bucketed edge partition ==============================

__global__ __launch_bounds__(256) void part1(const int* __restrict__ src,
                                             const int* __restrict__ dst,
                                             int* __restrict__ gcur,
                                             long long* __restrict__ ebuf) {
    __shared__ int cnt[256], sex[256], base[256], cur2[256], scn[256];
    __shared__ long long stage[P1E];
    const int tid = threadIdx.x;
    const int e0 = blockIdx.x * P1E;
    const int e1 = min(e0 + P1E, NE);
    cnt[tid] = 0;
    __syncthreads();
    for (int i = e0 + tid; i < e1; i += 256)
        atomicAdd(&cnt[dst[i] >> 9], 1);
    __syncthreads();
    int v = cnt[tid];
    scn[tid] = v;
    __syncthreads();
    #pragma unroll
    for (int off = 1; off < 256; off <<= 1) {
        int t = (tid >= off) ? scn[tid - off] : 0;
        __syncthreads();
        scn[tid] += t;
        __syncthreads();
    }
    sex[tid] = scn[tid] - v;
    if (tid < NBUC) base[tid] = (v > 0) ? atomicAdd(&gcur[tid], v) : 0;
    cur2[tid] = 0;
    __syncthreads();
    for (int i = e0 + tid; i < e1; i += 256) {
        int d = dst[i], s = src[i];
        int b = d >> 9;
        int slot = sex[b] + atomicAdd(&cur2[b], 1);
        stage[slot] = ((long long)(u32)d << 32) | (u32)s;
    }
    __syncthreads();
    const int tot = e1 - e0;
    for (int i = tid; i < tot; i += 256) {
        long long ll = stage[i];
        int b = (int)((u64)ll >> 32) >> 9;
        ebuf[(size_t)base[b] + (i - sex[b])] = ll;
    }
}

// per bucket: count per node, scan -> rowptr, scatter -> csrc (coalesced)
__global__ __launch_bounds__(256) void part2B(const int* __restrict__ bbase,
                                              const long long* __restrict__ ebuf,
                                              int* __restrict__ rowptr,
                                              int* __restrict__ csrc) {
    __shared__ int nb[NPB], cnt[NPB];
    __shared__ int stage[CAPB];
    __shared__ int ssum[256];
    const int tid = threadIdx.x;
    const int n0 = blockIdx.x << 9;
    const int nn = min(NPB, NN - n0);
    const int estart = bbase[blockIdx.x];
    const int eend = bbase[blockIdx.x + 1];
    const int tot = eend - estart;
    for (int i = tid; i < NPB; i += 256) cnt[i] = 0;
    __syncthreads();
    for (int i = estart + tid; i < eend; i += 256) {
        int ln = (int)((u64)ebuf[i] >> 32) - n0;
        atomicAdd(&cnt[ln], 1);
    }
    __syncthreads();
    // 512-scan (2 elems/thread)
    int a = cnt[2 * tid], b = cnt[2 * tid + 1];
    int ts = a + b;
    ssum[tid] = ts;
    __syncthreads();
    #pragma unroll
    for (int off = 1; off < 256; off <<= 1) {
        int t = (tid >= off) ? ssum[tid - off] : 0;
        __syncthreads();
        ssum[tid] += t;
        __syncthreads();
    }
    int eb = ssum[tid] - ts;  // exclusive
    nb[2 * tid] = eb;
    nb[2 * tid + 1] = eb + a;
    if (2 * tid < nn)     rowptr[n0 + 2 * tid]     = estart + eb;
    if (2 * tid + 1 < nn) rowptr[n0 + 2 * tid + 1] = estart + eb + a;
    if (tid == 0 && blockIdx.x == gridDim.x - 1) rowptr[NN] = eend;
    __syncthreads();
    for (int i = tid; i < NPB; i += 256) cnt[i] = 0;
    __syncthreads();
    if (tot <= CAPB) {
        for (int i = estart + tid; i < eend; i += 256) {
            long long ll = ebuf[i];
            int ln = (int)((u64)ll >> 32) - n0;
            int pos = nb[ln] + atomicAdd(&cnt[ln], 1);
            stage[pos] = (int)ll;
        }
        __syncthreads();
        for (int i = tid; i < tot; i += 256) csrc[estart + i] = stage[i];
    } else {
        for (int i = estart + tid; i < eend; i += 256) {
            long long ll = ebuf[i];
            int ln = (int)((u64)ll >> 32) - n0;
            int pos = nb[ln] + atomicAdd(&cnt[ln], 1);
            csrc[estart + pos] = (int)ll;
        }
    }
}

// ============================== weight prep (fused 3 layers) ==============================

__global__ void transW3(const float* __restrict__ W1, u16* __restrict__ W1t,
                        const float* __restrict__ W2, u16* __restrict__ W2t,
                        const float* __restrict__ W3, u16* __restrict__ W3t) {
    int idx = blockIdx.x * 256 + threadIdx.x;
    if (idx < 32768) {
        int n = idx / 256, k = idx % 256;
        W1t[idx] = f2b(W1[(size_t)k * 128 + n]);
    } else if (idx < 32768 + 16384) {
        int j = idx - 32768;
        int n = j / 128, k = j % 128;
        W2t[j] = f2b(W2[(size_t)k * 128 + n]);
    } else if (idx < 32768 + 16384 + 6144) {
        int j = idx - 32768 - 16384;
        int n = j / 128, k = j % 128;
        W3t[j] = f2b((n < 40) ? W3[(size_t)k * 40 + n] : 0.f);
    }
}

// ============================== MFMA GEMM (unchanged from R10) ==============================
template<int K, int NT, int OUTW, bool AF32, int NH>
__global__ __launch_bounds__(256, 4) void gemm_s(const void* __restrict__ Ap_,
                                                 const u16* __restrict__ Wt,
                                                 const float* __restrict__ al,
                                                 const float* __restrict__ ar,
                                                 u16* __restrict__ C,
                                                 float* __restrict__ el,
                                                 float* __restrict__ er, int M) {
    constexpr int KC = 128;
    constexpr int NKC = K / KC;
    constexpr int NB = NT * 16;
    constexpr int CHK = KC / 8;
    __shared__ u16 lB[NB * KC];
    const int tid = threadIdx.x;
    const int w = tid >> 6, l = tid & 63;
    const int lr = l & 15, lq = l >> 4;
    const int row0 = blockIdx.x * 64 + w * 16;
    const u16* Ab = (const u16*)Ap_;
    const float* Af = (const float*)Ap_;

    int gr0 = row0 + lr; if (gr0 >= M) gr0 = M - 1;
    const size_t aoff = (size_t)gr0 * K;

    f32x4 acc[NT] = {};
    #pragma unroll
    for (int kc = 0; kc < NKC; ++kc) {
        for (int idx = tid; idx < NB * CHK; idx += 256) {
            int row = idx / CHK, c = idx % CHK;
            float4 v = *reinterpret_cast<const float4*>(&Wt[(size_t)row * K + kc * KC + c * 8]);
            int cs = c ^ (row & 7);
            *reinterpret_cast<float4*>(&lB[row * KC + cs * 8]) = v;
        }
        __syncthreads();
        bf16x8 a0, a1, a2, a3;
        if (AF32) {
            float4 v[8];
            #pragma unroll
            for (int i = 0; i < 8; ++i)
                v[i] = *reinterpret_cast<const float4*>(
                    &Af[aoff + kc * KC + (i >> 1) * 32 + lq * 8 + (i & 1) * 4]);
            bf16x8 t[4];
            #pragma unroll
            for (int i = 0; i < 4; ++i) {
                t[i][0] = (short)f2b(v[2 * i].x); t[i][1] = (short)f2b(v[2 * i].y);
                t[i][2] = (short)f2b(v[2 * i].z); t[i][3] = (short)f2b(v[2 * i].w);
                t[i][4] = (short)f2b(v[2 * i + 1].x); t[i][5] = (short)f2b(v[2 * i + 1].y);
                t[i][6] = (short)f2b(v[2 * i + 1].z); t[i][7] = (short)f2b(v[2 * i + 1].w);
            }
            a0 = t[0]; a1 = t[1]; a2 = t[2]; a3 = t[3];
        } else {
            a0 = *reinterpret_cast<const bf16x8*>(&Ab[aoff + kc * KC + 0 * 32 + lq * 8]);
            a1 = *reinterpret_cast<const bf16x8*>(&Ab[aoff + kc * KC + 1 * 32 + lq * 8]);
            a2 = *reinterpret_cast<const bf16x8*>(&Ab[aoff + kc * KC + 2 * 32 + lq * 8]);
            a3 = *reinterpret_cast<const bf16x8*>(&Ab[aoff + kc * KC + 3 * 32 + lq * 8]);
        }
        #pragma unroll
        for (int ks = 0; ks < 4; ++ks) {
            bf16x8 aF = (ks == 0) ? a0 : (ks == 1) ? a1 : (ks == 2) ? a2 : a3;
            const int cs = (ks * 4 + lq) ^ (lr & 7);
            #pragma unroll
            for (int nr = 0; nr < NT; ++nr) {
                bf16x8 bF = *reinterpret_cast<const bf16x8*>(&lB[(nr * 16 + lr) * KC + cs * 8]);
                acc[nr] = __builtin_amdgcn_mfma_f32_16x16x32_bf16(aF, bF, acc[nr], 0, 0, 0);
            }
        }
        if (kc + 1 < NKC) __syncthreads();
    }

    float alv[NT], arv[NT];
    #pragma unroll
    for (int nr = 0; nr < NT; ++nr) {
        int c = nr * 16 + lr;
        alv[nr] = (c < OUTW) ? al[c] : 0.f;
        arv[nr] = (c < OUTW) ? ar[c] : 0.f;
    }
    #pragma unroll
    for (int reg = 0; reg < 4; ++reg) {
        int gr = row0 + lq * 4 + reg;
        bool ok = gr < M;
        if (ok) {
            #pragma unroll
            for (int nr = 0; nr < NT; ++nr) {
                int gc = nr * 16 + lr;
                if (gc < OUTW) C[(size_t)gr * OUTW + gc] = f2b(acc[nr][reg]);
            }
        }
        float pl[NH] = {}, pr[NH] = {};
        #pragma unroll
        for (int nr = 0; nr < NT; ++nr) {
            int hidx = (NH == 1) ? 0 : (nr >> 1);
            pl[hidx] = fmaf(acc[nr][reg], alv[nr], pl[hidx]);
            pr[hidx] = fmaf(acc[nr][reg], arv[nr], pr[hidx]);
        }
        #pragma unroll
        for (int o = 8; o >= 1; o >>= 1) {
            #pragma unroll
            for (int hh = 0; hh < NH; ++hh) {
                pl[hh] += __shfl_xor(pl[hh], o);
                pr[hh] += __shfl_xor(pr[hh], o);
            }
        }
        if (ok && lr == 0) {
            #pragma unroll
            for (int hh = 0; hh < NH; ++hh) {
                el[gr * NH + hh] = pl[hh];
                er[gr * NH + hh] = pr[hh];
            }
        }
    }
}

// ============================== aggregation v6 ==============================
// 8 nodes/block. Phase 1 block-cooperative (idle waves branch over). Phase 2:
// each wave 2 nodes, interleaved ILP-4 gather chains (8 loads in flight).

template<bool RELU>
__global__ __launch_bounds__(256) void agg4v6(const char* __restrict__ hbase,
                                              const float4* __restrict__ el4,
                                              const float4* __restrict__ er4,
                                              const float* __restrict__ bias,
                                              const int* __restrict__ rowptr,
                                              const int* __restrict__ csrc,
                                              u32* __restrict__ out, int N) {
    __shared__ u32 s_ed[BCAP][8];
    __shared__ int s_off[9];
    const int tid = threadIdx.x, w = tid >> 6, lane = tid & 63;
    const int base = blockIdx.x * 8;
    if (tid < 9) {
        int n = base + tid;
        s_off[tid] = rowptr[n <= N ? n : N];
    }
    __syncthreads();
    const int beg_blk = s_off[0];
    const int T = s_off[8] - beg_blk;
    const int hh = lane >> 4;
    const u32 lshl = (u32)(lane << 2);
    const float2 bv = reinterpret_cast<const float2*>(bias)[lane];
    const bool small = (T <= BCAP);

    if (small) {
        for (int t = tid; t < T; t += 256) {
            int sid = csrc[beg_blk + t];
            int nd = 0;
            #pragma unroll
            for (int k = 1; k < 8; ++k) nd += (t >= (s_off[k] - beg_blk)) ? 1 : 0;
            float4 er = er4[base + nd];
            float4 ev = el4[sid];
            float e0 = ev.x + er.x; e0 = e0 > 0.f ? e0 : 0.2f * e0;
            float e1 = ev.y + er.y; e1 = e1 > 0.f ? e1 : 0.2f * e1;
            float e2 = ev.z + er.z; e2 = e2 > 0.f ? e2 : 0.2f * e2;
            float e3 = ev.w + er.w; e3 = e3 > 0.f ? e3 : 0.2f * e3;
            u32 so = (u32)sid << 8;
            *reinterpret_cast<int2*>(&s_ed[t][0]) = make_int2(__float_as_int(__expf(e0)), (int)so);
            *reinterpret_cast<int2*>(&s_ed[t][2]) = make_int2(__float_as_int(__expf(e1)), (int)so);
            *reinterpret_cast<int2*>(&s_ed[t][4]) = make_int2(__float_as_int(__expf(e2)), (int)so);
            *reinterpret_cast<int2*>(&s_ed[t][6]) = make_int2(__float_as_int(__expf(e3)), (int)so);
        }
    }
    __syncthreads();

    const int nA = base + 2 * w;
    if (nA >= N) return;
    const int nB = nA + 1;
    float aA[4] = {}, bA[4] = {}, sA[4] = {};
    float aB[4] = {}, bB[4] = {}, sB[4] = {};

    if (small) {
        const int oA0 = s_off[2 * w] - beg_blk, oA1 = s_off[2 * w + 1] - beg_blk;
        const int oB0 = oA1, oB1 = s_off[2 * w + 2] - beg_blk;
        const int dA = oA1 - oA0, dB = oB1 - oB0;
        const int it = max((dA + 3) >> 2, (dB + 3) >> 2);
        for (int i = 0; i < it; ++i) {
            const int pA = oA0 + i * 4, pB = oB0 + i * 4;
            #pragma unroll
            for (int k = 0; k < 4; ++k) {
                int j = pA + k; bool v = j < oA1;
                int2 rv = *reinterpret_cast<const int2*>(&s_ed[v ? j : 0][hh * 2]);
                float wg = v ? __int_as_float(rv.x) : 0.f;
                u32 hv = *reinterpret_cast<const u32*>(hbase + ((u32)rv.y | lshl));
                aA[k] = fmaf(wg, bflo(hv), aA[k]);
                bA[k] = fmaf(wg, bfhi(hv), bA[k]);
                sA[k] += wg;
            }
            #pragma unroll
            for (int k = 0; k < 4; ++k) {
                int j = pB + k; bool v = j < oB1;
                int2 rv = *reinterpret_cast<const int2*>(&s_ed[v ? j : 0][hh * 2]);
                float wg = v ? __int_as_float(rv.x) : 0.f;
                u32 hv = *reinterpret_cast<const u32*>(hbase + ((u32)rv.y | lshl));
                aB[k] = fmaf(wg, bflo(hv), aB[k]);
                bB[k] = fmaf(wg, bfhi(hv), bB[k]);
                sB[k] += wg;
            }
        }
        {
            float accA = (aA[0] + aA[1]) + (aA[2] + aA[3]);
            float accB = (bA[0] + bA[1]) + (bA[2] + bA[3]);
            float s = (sA[0] + sA[1]) + (sA[2] + sA[3]);
            float invs = (dA > 0) ? 1.f / s : 0.f;
            float oA = accA * invs + bv.x;
            float oB = accB * invs + bv.y;
            if (RELU) { oA = fmaxf(oA, 0.f); oB = fmaxf(oB, 0.f); }
            out[(size_t)nA * 64 + lane] = ((u32)f2b(oB) << 16) | (u32)f2b(oA);
        }
        {
            float accA = (aB[0] + aB[1]) + (aB[2] + aB[3]);
            float accB = (bB[0] + bB[1]) + (bB[2] + bB[3]);
            float s = (sB[0] + sB[1]) + (sB[2] + sB[3]);
            float invs = (dB > 0) ? 1.f / s : 0.f;
            float oA = accA * invs + bv.x;
            float oB = accB * invs + bv.y;
            if (RELU) { oA = fmaxf(oA, 0.f); oB = fmaxf(oB, 0.f); }
            if (nB < N)
                out[(size_t)nB * 64 + lane] = ((u32)f2b(oB) << 16) | (u32)f2b(oA);
        }
    } else {
        // streaming fallback (rare): nodes A and B sequentially
        #pragma unroll
        for (int which = 0; which < 2; ++which) {
            int nd = nA + which;
            if (nd >= N) break;
            int beg = s_off[2 * w + which], end = s_off[2 * w + which + 1];
            float4 er = er4[nd];
            float er_h = hh == 0 ? er.x : hh == 1 ? er.y : hh == 2 ? er.z : er.w;
            float s = 0.f, accA = 0.f, accB = 0.f;
            for (int q = beg; q < end; ++q) {
                int sid = csrc[q];
                float4 ev = el4[sid];
                float e = (hh == 0 ? ev.x : hh == 1 ? ev.y : hh == 2 ? ev.z : ev.w) + er_h;
                e = e > 0.f ? e : 0.2f * e;
                float pe = __expf(e);
                u32 hv = *reinterpret_cast<const u32*>(hbase + (((u32)sid << 8) | lshl));
                s += pe;
                accA = fmaf(pe, bflo(hv), accA);
                accB = fmaf(pe, bfhi(hv), accB);
            }
            float invs = (end > beg) ? 1.f / s : 0.f;
            float oA = accA * invs + bv.x;
            float oB = accB * invs + bv.y;
            if (RELU) { oA = fmaxf(oA, 0.f); oB = fmaxf(oB, 0.f); }
            out[(size_t)nd * 64 + lane] = ((u32)f2b(oB) << 16) | (u32)f2b(oA);
        }
    }
}

// single head + bias + log_softmax(40); h3 [N,40] bf16
__global__ __launch_bounds__(256) void agg1v6(const char* __restrict__ hbase,
                                              const float* __restrict__ el,
                                              const float* __restrict__ er,
                                              const float* __restrict__ bias,
                                              const int* __restrict__ rowptr,
                                              const int* __restrict__ csrc,
                                              float* __restrict__ out, int N) {
    __shared__ u32 s_e1[BCAP][2];
    __shared__ int s_off[9];
    const int tid = threadIdx.x, w = tid >> 6, lane = tid & 63;
    const int base = blockIdx.x * 8;
    if (tid < 9) {
        int n = base + tid;
        s_off[tid] = rowptr[n <= N ? n : N];
    }
    __syncthreads();
    const int beg_blk = s_off[0];
    const int T = s_off[8] - beg_blk;
    const int ll = lane < 40 ? lane : 39;
    const u32 lloff = (u32)(ll << 1);
    const float bvv = (lane < 40) ? bias[lane] : 0.f;
    const bool small = (T <= BCAP);

    if (small) {
        for (int t = tid; t < T; t += 256) {
            int sid = csrc[beg_blk + t];
            int nd = 0;
            #pragma unroll
            for (int k = 1; k < 8; ++k) nd += (t >= (s_off[k] - beg_blk)) ? 1 : 0;
            float e = el[sid] + er[base + nd];
            e = e > 0.f ? e : 0.2f * e;
            *reinterpret_cast<int2*>(&s_e1[t][0]) =
                make_int2(__float_as_int(__expf(e)), (int)((u32)sid * 80u));
        }
    }
    __syncthreads();

    const int nA = base + 2 * w;
    if (nA >= N) return;
    const int nB = nA + 1;
    float aA[4] = {}, sA[4] = {}, aB[4] = {}, sB[4] = {};
    float accA, invsA, accB, invsB;
    bool haveB = (nB < N);

    if (small) {
        const int oA0 = s_off[2 * w] - beg_blk, oA1 = s_off[2 * w + 1] - beg_blk;
        const int oB0 = oA1, oB1 = s_off[2 * w + 2] - beg_blk;
        const int dA = oA1 - oA0, dB = oB1 - oB0;
        const int it = max((dA + 3) >> 2, (dB + 3) >> 2);
        for (int i = 0; i < it; ++i) {
            const int pA = oA0 + i * 4, pB = oB0 + i * 4;
            #pragma unroll
            for (int k = 0; k < 4; ++k) {
                int j = pA + k; bool v = j < oA1;
                int2 rv = *reinterpret_cast<const int2*>(&s_e1[v ? j : 0][0]);
                float wg = v ? __int_as_float(rv.x) : 0.f;
                u16 hv = *reinterpret_cast<const u16*>(hbase + ((u32)rv.y + lloff));
                aA[k] = fmaf(wg, b2f(hv), aA[k]);
                sA[k] += wg;
            }
            #pragma unroll
            for (int k = 0; k < 4; ++k) {
                int j = pB + k; bool v = j < oB1;
                int2 rv = *reinterpret_cast<const int2*>(&s_e1[v ? j : 0][0]);
                float wg = v ? __int_as_float(rv.x) : 0.f;
                u16 hv = *reinterpret_cast<const u16*>(hbase + ((u32)rv.y + lloff));
                aB[k] = fmaf(wg, b2f(hv), aB[k]);
                sB[k] += wg;
            }
        }
        accA = (aA[0] + aA[1]) + (aA[2] + aA[3]);
        float ssA = (sA[0] + sA[1]) + (sA[2] + sA[3]);
        invsA = (dA > 0) ? 1.f / ssA : 0.f;
        accB = (aB[0] + aB[1]) + (aB[2] + aB[3]);
        float ssB = (sB[0] + sB[1]) + (sB[2] + sB[3]);
        invsB = (dB > 0) ? 1.f / ssB : 0.f;
    } else {
        accA = 0.f; accB = 0.f; invsA = 0.f; invsB = 0.f;
        #pragma unroll
        for (int which = 0; which < 2; ++which) {
            int nd = nA + which;
            if (nd >= N) break;
            int beg = s_off[2 * w + which], end = s_off[2 * w + which + 1];
            float ern = er[nd];
            float s = 0.f, acc = 0.f;
            for (int q = beg; q < end; ++q) {
                int sid = csrc[q];
                float e = el[sid] + ern; e = e > 0.f ? e : 0.2f * e;
                float pe = __expf(e);
                u16 hv = *reinterpret_cast<const u16*>(hbase + ((u32)sid * 80u + lloff));
                s += pe;
                acc = fmaf(pe, b2f(hv), acc);
            }
            float inv = (end > beg) ? 1.f / s : 0.f;
            if (which == 0) { accA = acc; invsA = inv; }
            else { accB = acc; invsB = inv; }
        }
    }
    // log-softmax per node
    {
        float v = accA * invsA + bvv;
        float vv = (lane < 40) ? v : -INFINITY;
        float mx = vv;
        #pragma unroll
        for (int o = 32; o >= 1; o >>= 1) mx = fmaxf(mx, __shfl_xor(mx, o));
        float ex = (lane < 40) ? __expf(v - mx) : 0.f;
        float se = ex;
        #pragma unroll
        for (int o = 32; o >= 1; o >>= 1) se += __shfl_xor(se, o);
        if (lane < 40) out[(size_t)nA * 40 + lane] = v - mx - logf(se);
    }
    if (haveB) {
        float v = accB * invsB + bvv;
        float vv = (lane < 40) ? v : -INFINITY;
        float mx = vv;
        #pragma unroll
        for (int o = 32; o >= 1; o >>= 1) mx = fmaxf(mx, __shfl_xor(mx, o));
        float ex = (lane < 40) ? __expf(v - mx) : 0.f;
        float se = ex;
        #pragma unroll
        for (int o = 32; o >= 1; o >>= 1) se += __shfl_xor(se, o);
        if (lane < 40) out[(size_t)nB * 40 + lane] = v - mx - logf(se);
    }
}

// ============================== launch ==============================

extern "C" void kernel_launch(void* const* d_in, const int* in_sizes, int n_in,
                              void* d_out, int out_size, void* d_ws, size_t ws_size,
                              hipStream_t stream) {
    const float* feat = (const float*)d_in[0];
    const float* W1  = (const float*)d_in[1];
    const float* al1 = (const float*)d_in[2];
    const float* ar1 = (const float*)d_in[3];
    const float* b1  = (const float*)d_in[4];
    const float* W2  = (const float*)d_in[5];
    const float* al2 = (const float*)d_in[6];
    const float* ar2 = (const float*)d_in[7];
    const float* b2  = (const float*)d_in[8];
    const float* W3  = (const float*)d_in[9];
    const float* al3 = (const float*)d_in[10];
    const float* ar3 = (const float*)d_in[11];
    const float* b3  = (const float*)d_in[12];
    const int*   src = (const int*)d_in[13];
    const int*   dst = (const int*)d_in[14];
    float* out = (float*)d_out;
    const int N = NN, E = NE;

    char* ws = (char*)d_ws;
    size_t off = 0;
    auto alloc = [&](size_t bytes) -> char* {
        char* p = ws + off;
        off += (bytes + 255) & ~(size_t)255;
        return p;
    };
    int* bcnt   = (int*)alloc(256 * 4);
    int* bbase  = (int*)alloc(256 * 4);
    int* gcur   = (int*)alloc(256 * 4);
    int* rowptr = (int*)alloc((size_t)(N + 1) * 4);
    int* csrc   = (int*)alloc((size_t)E * 4);
    long long* ebuf = (long long*)alloc((size_t)E * 8);
    float* el   = (float*)alloc((size_t)N * 4 * 4);
    float* er   = (float*)alloc((size_t)N * 4 * 4);
    u16* hb     = (u16*)alloc((size_t)N * 128 * 2);
    u16* xb     = (u16*)alloc((size_t)N * 128 * 2);
    u16* h3     = (u16*)alloc((size_t)N * 40 * 2 + 256);
    u16* W1t    = (u16*)alloc((size_t)128 * 256 * 2);
    u16* W2t    = (u16*)alloc((size_t)128 * 128 * 2);
    u16* W3t    = (u16*)alloc((size_t)48 * 128 * 2);

    // ---- CSR build (bucket count -> scan -> partition -> per-bucket scatter+rowptr) ----
    hipMemsetAsync(bcnt, 0, NBUC * 4, stream);
    bucket_cnt<<<1024, 256, 0, stream>>>(dst, bcnt, E);
    bucket_scan<<<1, 256, 0, stream>>>(bcnt, bbase, gcur);
    part1<<<P1B, 256, 0, stream>>>(src, dst, gcur, ebuf);
    part2B<<<NBUC, 256, 0, stream>>>(bbase, ebuf, rowptr, csrc);

    // ---- weight prep ----
    transW3<<<(32768 + 16384 + 6144 + 255) / 256, 256, 0, stream>>>(W1, W1t, W2, W2t, W3, W3t);

    int gemmGrid = (N + 63) / 64;
    int aggGrid = (N + 7) / 8;

    // ---- layer 1 ----
    gemm_s<256, 8, 128, true, 4><<<gemmGrid, 256, 0, stream>>>(feat, W1t, al1, ar1, hb, el, er, N);
    agg4v6<true><<<aggGrid, 256, 0, stream>>>((const char*)hb, (const float4*)el, (const float4*)er,
                                              b1, rowptr, csrc, (u32*)xb, N);

    // ---- layer 2 ----
    gemm_s<128, 8, 128, false, 4><<<gemmGrid, 256, 0, stream>>>(xb, W2t, al2, ar2, hb, el, er, N);
    agg4v6<true><<<aggGrid, 256, 0, stream>>>((const char*)hb, (const float4*)el, (const float4*)er,
                                              b2, rowptr, csrc, (u32*)xb, N);

    // ---- layer 3 (+ fused log_softmax) ----
    gemm_s<128, 3, 40, false, 1><<<gemmGrid, 256, 0, stream>>>(xb, W3t, al3, ar3, h3, el, er, N);
    agg1v6<<<aggGrid, 256, 0, stream>>>((const char*)h3, el, er, b3, rowptr, csrc, out, N);
}